// Round 6
// baseline (7299.434 us; speedup 1.0000x reference)
//
#include <hip/hip_runtime.h>
#include <stdint.h>

#define Bv 64
#define Tv 2048
#define T1v 1024
#define Dv 128
#define Hv 256

typedef _Float16 h2_t __attribute__((ext_vector_type(2)));

__device__ inline float d2(uint32_t hp, uint32_t wp, float acc) {
#if __has_builtin(__builtin_amdgcn_fdot2)
  return __builtin_amdgcn_fdot2(__builtin_bit_cast(h2_t, hp),
                                __builtin_bit_cast(h2_t, wp), acc, false);
#else
  float out;
  asm("v_dot2_f32_f16 %0, %1, %2, %3" : "=v"(out) : "v"(hp), "v"(wp), "v"(acc));
  return out;
#endif
}

__device__ inline uint16_t f2h(float x) {
  _Float16 h = (_Float16)x;
  return __builtin_bit_cast(uint16_t, h);
}
__device__ inline float h2f(uint16_t u) {
  return (float)__builtin_bit_cast(_Float16, u);
}
__device__ inline uint32_t packpair(float a, float b) {
  return (uint32_t)f2h(a) | ((uint32_t)f2h(b) << 16);
}
__device__ inline float unpk(uint32_t u, int hi) {
  return h2f((uint16_t)(hi ? (u >> 16) : (u & 0xffff)));
}
__device__ inline float sigm(float x) { return 1.f / (1.f + __expf(-x)); }
__device__ inline float tanh_(float x) { return 2.f / (1.f + __expf(-2.f * x)) - 1.f; }

// butterfly sum over the 4 lanes of a quad (VALU DPP, no LDS)
__device__ inline float qsum4(float v) {
  int t = __builtin_amdgcn_update_dpp(0, __float_as_int(v), 0xB1, 0xF, 0xF, true);
  v += __int_as_float(t);
  t = __builtin_amdgcn_update_dpp(0, __float_as_int(v), 0x4E, 0xF, 0xF, true);
  return v + __int_as_float(t);
}

// volatile scalarized 16B load: not hoistable by LICM (stays a per-step L2 stream)
__device__ inline uint4 ld_stream(const uint4* p) {
  const volatile uint32_t* q = (const volatile uint32_t*)p;
  uint4 v;
  v.x = q[0];
  v.y = q[1];
  v.z = q[2];
  v.w = q[3];
  return v;
}

// ---------------- prep kernels ----------------

__global__ void k_pack_x(const float* __restrict__ x, uint32_t* __restrict__ xpk) {
  int idx = blockIdx.x * 256 + threadIdx.x;  // B*T*64
  const float2* x2 = (const float2*)x;
  float2 v = x2[idx];
  xpk[idx] = packpair(v.x, v.y);
}

// OLD layout (fallback kernel k_rnn5)
__global__ void k_pack_w(const float* __restrict__ src, uint32_t* __restrict__ wAll,
                         uint32_t* __restrict__ wLg, uint32_t* __restrict__ wStr) {
  int idx = blockIdx.x * 256 + threadIdx.x;  // 1024*128
  int row = idx >> 7, k2 = idx & 127;
  uint32_t pr = packpair(src[row * 256 + 2 * k2], src[row * 256 + 2 * k2 + 1]);
  wAll[k2 * 1024 + row] = pr;
  if (k2 >= 96) {
    int g = (k2 - 96) >> 2, qq = (k2 - 96) & 3;
    wLg[(g * 1024 + row) * 4 + qq] = pr;
  }
  if (k2 >= 48 && k2 < 96) wStr[row * 48 + (k2 - 48)] = pr;
}

// NEW layout (k_rnnU): thread tid = jb*4+q owns rows r(ri)=gate*256+jb+128*u_hi,
// ri = u_hi*4+gate, pairs k2 in [32q,32q+32), kk = k2-32q.
// kk<24  -> wSt  uint4 chunk cc=kk>>2:  wSt [(ri*6+cc)*512+tid]
// kk>=24 -> wLds uint4 chunk p=(kk-24)>>2: wLds[(ri*2+p )*512+tid]
__global__ void k_pack_w2(const float* __restrict__ src, uint32_t* __restrict__ wSt,
                          uint32_t* __restrict__ wLds) {
  int idx = blockIdx.x * 256 + threadIdx.x;  // 1024*128
  int r = idx >> 7, k2 = idx & 127;
  uint32_t pr = packpair(src[r * 256 + 2 * k2], src[r * 256 + 2 * k2 + 1]);
  int gate = r >> 8, u = r & 255;
  int u_hi = u >> 7, jb = u & 127;
  int q = k2 >> 5, kk = k2 & 31;
  int tid = jb * 4 + q;
  int ri = u_hi * 4 + gate;
  if (kk < 24) {
    wSt[((ri * 6 + (kk >> 2)) * 512 + tid) * 4 + (kk & 3)] = pr;
  } else {
    wLds[((ri * 2 + ((kk - 24) >> 2)) * 512 + tid) * 4 + ((kk - 24) & 3)] = pr;
  }
}

// bias packed f16: bpk[jb] = uint4, word wi = (bias[row(2wi)], bias[row(2wi+1)])
__global__ void k_bias_pack(const float* __restrict__ b32, uint32_t* __restrict__ bpk) {
  int jb = threadIdx.x;  // 128
  uint32_t w[4];
#pragma unroll
  for (int wi = 0; wi < 4; ++wi) {
    int ri0 = 2 * wi, ri1 = 2 * wi + 1;
    int row0 = (ri0 & 3) * 256 + jb + 128 * (ri0 >> 2);
    int row1 = (ri1 & 3) * 256 + jb + 128 * (ri1 >> 2);
    w[wi] = packpair(b32[row0], b32[row1]);
  }
  ((uint4*)bpk)[jb] = make_uint4(w[0], w[1], w[2], w[3]);
}

__global__ void k_pack_wih(const float* __restrict__ Wih, uint32_t* __restrict__ wihp) {
  int idx = blockIdx.x * 256 + threadIdx.x;  // 1024*64
  int row = idx >> 6, k2 = idx & 63;
  wihp[row * 64 + k2] = packpair(Wih[row * 128 + 2 * k2], Wih[row * 128 + 2 * k2 + 1]);
}

__global__ void k_bias2(const float* __restrict__ bih, const float* __restrict__ bhh,
                        float* __restrict__ bias) {
  int i = blockIdx.x * 256 + threadIdx.x;
  if (i < 1024) bias[i] = bih[i] + bhh[i];
}

__global__ void k_dec_combine(const float* __restrict__ Whh, const float* __restrict__ Wih,
                              const float* __restrict__ bih, const float* __restrict__ bhh,
                              const float* __restrict__ lW, const float* __restrict__ lb,
                              float* __restrict__ wd, float* __restrict__ bias) {
  int j = blockIdx.x;
  int k = threadIdx.x;
  __shared__ float wr[128];
  if (k < 128) wr[k] = Wih[j * 128 + k];
  __syncthreads();
  float acc = Whh[j * 256 + k];
  for (int d = 0; d < 128; ++d) acc += wr[d] * lW[d * 256 + k];
  wd[j * 256 + k] = acc;
  if (k == 0) {
    float s = bih[j] + bhh[j];
    for (int d = 0; d < 128; ++d) s += wr[d] * lb[d];
    bias[j] = s;
  }
}

__global__ void k_pack_wl(const float* __restrict__ lW, uint32_t* __restrict__ wlp) {
  int idx = blockIdx.x * 256 + threadIdx.x;  // 128*128
  int d = idx >> 7, k2 = idx & 127;
  wlp[d * 128 + k2] = packpair(lW[d * 256 + 2 * k2], lW[d * 256 + 2 * k2 + 1]);
}

// Xp precompute. LAY=0: xp[((b*1024+s)*128+jb)*8 + ri]; LAY=1: xp[(b*1024+s)*1024 + r]
template <int LAY>
__global__ __launch_bounds__(256) void k_xp_gemm(const uint32_t* __restrict__ xpk,
                                                 const uint32_t* __restrict__ wihp,
                                                 uint16_t* __restrict__ xp, int xt0, int xdt) {
  const int b = blockIdx.z;
  const int s0 = blockIdx.y * 32;
  const int r = blockIdx.x * 256 + threadIdx.x;
  uint32_t wreg[64];
#pragma unroll
  for (int k = 0; k < 64; ++k) wreg[k] = wihp[r * 64 + k];
  const int gate = r >> 8, u = r & 255;
  const int u_hi = u >> 7, jb = u & 127;
  const int ri = u_hi * 4 + gate;
  for (int sl = 0; sl < 32; ++sl) {
    const int s = s0 + sl;
    const int t = xt0 + s * xdt;
    const uint32_t* __restrict__ xrow = xpk + ((size_t)b * Tv + t) * 64;
    float a0 = 0.f, a1 = 0.f;
#pragma unroll
    for (int k = 0; k < 64; k += 2) {
      a0 = d2(xrow[k], wreg[k], a0);
      a1 = d2(xrow[k + 1], wreg[k + 1], a1);
    }
    uint16_t v = f2h(a0 + a1);
    if (LAY == 0)
      xp[(((size_t)b * T1v + s) * 128 + jb) * 8 + ri] = v;
    else
      xp[((size_t)b * T1v + s) * 1024 + r] = v;
  }
}

// ---------------- NEW recurrence kernel (unit-fused, K-split 4) ----------------

struct CfgU {
  const uint4* wSt;   // [48][512] chunks cc 0..5 per row
  const uint4* wLds;  // [16][512] chunks cc 6..7 per row
  const uint4* bpk;   // [128]
  const uint4* xps;   // [B][1024][128] or null
  const float* h0;
  const float* c0;
  float* hN;
  float* cN;
  uint16_t* hist;  // [B][1024][256] or null
};

// per row (8 rows/thread): NREGC chunks in VGPR/AGPR, NSTRC streamed from L2
// (volatile, per step), NLDSC from LDS. NREGC+NSTRC+NLDSC == 8.
template <int NREGC, int NSTRC, int NLDSC>
__global__ void __launch_bounds__(512)
__attribute__((amdgpu_waves_per_eu(2, 2)))
k_rnnU(CfgU cA, CfgU cB, int nA) {
  __shared__ __align__(16) uint4 wldsM[NLDSC * 8 * 512];
  __shared__ __align__(16) uint16_t hbuf[2][4][72];  // padded: q-chunks bank-disjoint

  const bool isA = (int)blockIdx.x < nA;
  const CfgU cfg = isA ? cA : cB;
  const int b = isA ? (int)blockIdx.x : ((int)blockIdx.x - nA);
  const int tid = threadIdx.x;
  const int q = tid & 3, jb = tid >> 2;

#pragma unroll
  for (int ri = 0; ri < 8; ++ri)
#pragma unroll
    for (int li = 0; li < NLDSC; ++li)
      wldsM[(ri * NLDSC + li) * 512 + tid] =
          cfg.wLds[(ri * 2 + (2 - NLDSC) + li) * 512 + tid];

  uint4 wr[8][NREGC];
#pragma unroll
  for (int ri = 0; ri < 8; ++ri)
#pragma unroll
    for (int cc = 0; cc < NREGC; ++cc) wr[ri][cc] = cfg.wSt[(ri * 6 + cc) * 512 + tid];

  const uint4 bp = cfg.bpk[jb];
  float c0r = cfg.c0 ? cfg.c0[b * 256 + jb] : 0.f;
  float c1r = cfg.c0 ? cfg.c0[b * 256 + jb + 128] : 0.f;

  uint16_t* histp = cfg.hist ? cfg.hist + (size_t)b * 1024 * 256 : nullptr;
  if (q == 0) {
    float h00 = cfg.h0 ? cfg.h0[b * 256 + jb] : 0.f;
    float h01 = cfg.h0 ? cfg.h0[b * 256 + jb + 128] : 0.f;
    uint16_t u0 = f2h(h00), u1 = f2h(h01);
    hbuf[0][jb >> 6][jb & 63] = u0;
    hbuf[0][2 + (jb >> 6)][jb & 63] = u1;
    if (histp) {
      histp[jb] = u0;
      histp[jb + 128] = u1;
    }
  }
  const uint4* xps4 = cfg.xps ? cfg.xps + (size_t)b * 1024 * 128 + jb : nullptr;

  __syncthreads();

  int cur = 0;
  for (int s = 0; s < 1024; ++s) {
    uint4 xq = make_uint4(0, 0, 0, 0);
    if (xps4) xq = xps4[(size_t)s * 128];
    const uint4* Hq = (const uint4*)&hbuf[cur][q][0];

    float acc[8];
#pragma unroll
    for (int ri = 0; ri < 8; ++ri) acc[ri] = 0.f;

#pragma unroll
    for (int cc = 0; cc < NREGC; ++cc) {  // register-resident chunks
      const uint4 hv = Hq[cc];
#pragma unroll
      for (int ri = 0; ri < 8; ++ri) {
        acc[ri] = d2(hv.x, wr[ri][cc].x, acc[ri]);
        acc[ri] = d2(hv.y, wr[ri][cc].y, acc[ri]);
        acc[ri] = d2(hv.z, wr[ri][cc].z, acc[ri]);
        acc[ri] = d2(hv.w, wr[ri][cc].w, acc[ri]);
      }
    }
#pragma unroll
    for (int j = 0; j < NSTRC; ++j) {  // L2-streamed chunks (VMEM pipe)
      const int cc = NREGC + j;
      const uint4 hv = Hq[cc];
#pragma unroll
      for (int ri = 0; ri < 8; ++ri) {
        const uint4 wv = (cc < 6) ? ld_stream(cfg.wSt + (ri * 6 + cc) * 512 + tid)
                                  : ld_stream(cfg.wLds + (ri * 2 + (cc - 6)) * 512 + tid);
        acc[ri] = d2(hv.x, wv.x, acc[ri]);
        acc[ri] = d2(hv.y, wv.y, acc[ri]);
        acc[ri] = d2(hv.z, wv.z, acc[ri]);
        acc[ri] = d2(hv.w, wv.w, acc[ri]);
      }
    }
#pragma unroll
    for (int li = 0; li < NLDSC; ++li) {  // LDS chunks
      const int cc = 8 - NLDSC + li;
      const uint4 hv = Hq[cc];
#pragma unroll
      for (int ri = 0; ri < 8; ++ri) {
        const uint4 wv = wldsM[(ri * NLDSC + li) * 512 + tid];
        acc[ri] = d2(hv.x, wv.x, acc[ri]);
        acc[ri] = d2(hv.y, wv.y, acc[ri]);
        acc[ri] = d2(hv.z, wv.z, acc[ri]);
        acc[ri] = d2(hv.w, wv.w, acc[ri]);
      }
    }

#pragma unroll
    for (int ri = 0; ri < 8; ++ri) acc[ri] = qsum4(acc[ri]);

    acc[0] += unpk(bp.x, 0) + unpk(xq.x, 0);
    acc[1] += unpk(bp.x, 1) + unpk(xq.x, 1);
    acc[2] += unpk(bp.y, 0) + unpk(xq.y, 0);
    acc[3] += unpk(bp.y, 1) + unpk(xq.y, 1);
    acc[4] += unpk(bp.z, 0) + unpk(xq.z, 0);
    acc[5] += unpk(bp.z, 1) + unpk(xq.z, 1);
    acc[6] += unpk(bp.w, 0) + unpk(xq.w, 0);
    acc[7] += unpk(bp.w, 1) + unpk(xq.w, 1);

    const float cn0 = sigm(acc[1]) * c0r + sigm(acc[0]) * tanh_(acc[2]);
    const float h0v = sigm(acc[3]) * tanh_(cn0);
    c0r = cn0;
    const float cn1 = sigm(acc[5]) * c1r + sigm(acc[4]) * tanh_(acc[6]);
    const float h1v = sigm(acc[7]) * tanh_(cn1);
    c1r = cn1;

    if (q == 0) {
      const uint16_t hu0 = f2h(h0v), hu1 = f2h(h1v);
      hbuf[cur ^ 1][jb >> 6][jb & 63] = hu0;
      hbuf[cur ^ 1][2 + (jb >> 6)][jb & 63] = hu1;
      if (histp && s < 1023) {
        histp[(size_t)(s + 1) * 256 + jb] = hu0;
        histp[(size_t)(s + 1) * 256 + jb + 128] = hu1;
      }
    }
    __syncthreads();
    cur ^= 1;
  }

  if (cfg.hN && q == 0) {
    cfg.hN[b * 256 + jb] = h2f(hbuf[cur][jb >> 6][jb & 63]);
    cfg.hN[b * 256 + jb + 128] = h2f(hbuf[cur][2 + (jb >> 6)][jb & 63]);
    cfg.cN[b * 256 + jb] = c0r;
    cfg.cN[b * 256 + jb + 128] = c1r;
  }
}

// ---------------- OLD recurrence kernel (R4-proven fallback) ----------------

struct ChainCfg {
  const uint32_t* wAll;
  const uint4* wLg;
  const uint32_t* wStr;
  const uint32_t* wih;
  const uint32_t* xpk;
  const uint16_t* xps;  // old layout [B][1024][1024]
  const float* bias;
  const float* h0;
  const float* c0;
  float* hN;
  float* cN;
  uint16_t* hist;
  int xt0, xdt;
};

template <int NRESP, bool WIH>
__global__ void __launch_bounds__(512)
__attribute__((amdgpu_waves_per_eu(2, 2)))
k_rnn5(ChainCfg cA, ChainCfg cB, int nA) {
  __shared__ __align__(16) uint4 wlds4[8 * 1024];
  __shared__ float gsm[1024];
  __shared__ __align__(16) uint16_t h16[256];
  __shared__ __align__(16) uint32_t xsh[64];

  const bool isA = (int)blockIdx.x < nA;
  const ChainCfg cfg = isA ? cA : cB;
  const int b = isA ? (int)blockIdx.x : ((int)blockIdx.x - nA);
  const int tid = threadIdx.x;
  const int r0 = tid, r1 = tid + 512;

#pragma unroll
  for (int i = 0; i < 16; ++i) wlds4[i * 512 + tid] = cfg.wLg[i * 512 + tid];

  uint16_t* histp = cfg.hist ? cfg.hist + (size_t)b * 1024 * 256 : nullptr;

  float creg = 0.f;
  if (tid < 256) {
    float h0v = cfg.h0 ? cfg.h0[b * 256 + tid] : 0.f;
    creg = cfg.c0 ? cfg.c0[b * 256 + tid] : 0.f;
    uint16_t hu = f2h(h0v);
    h16[tid] = hu;
    if (histp) histp[tid] = hu;
  }

  uint32_t w0[NRESP], w1[NRESP];
#pragma unroll
  for (int k = 0; k < NRESP; ++k) w0[k] = cfg.wAll[k * 1024 + r0];
#pragma unroll
  for (int k = 0; k < NRESP; ++k) w1[k] = cfg.wAll[k * 1024 + r1];
  const float bias0 = cfg.bias[r0];
  const float bias1 = cfg.bias[r1];

  constexpr int NS4 = (96 - NRESP) / 4;
  const uint4* ws0 = (const uint4*)(cfg.wStr + (size_t)r0 * 48 + (NRESP - 48));
  const uint4* ws1 = (const uint4*)(cfg.wStr + (size_t)r1 * 48 + (NRESP - 48));
  const uint4* wi0 = cfg.wih ? (const uint4*)(cfg.wih + (size_t)r0 * 64) : nullptr;
  const uint4* wi1 = cfg.wih ? (const uint4*)(cfg.wih + (size_t)r1 * 64) : nullptr;
  const bool hasx = cfg.xps != nullptr;

  __syncthreads();

  for (int s = 0; s < 1024; ++s) {
    float xa0 = 0.f, xa1 = 0.f;
    if (hasx) {
      size_t xb = ((size_t)b * 1024 + s) * 1024;
      xa0 = h2f(cfg.xps[xb + r0]);
      xa1 = h2f(cfg.xps[xb + r1]);
    }
    if constexpr (WIH) {
      if (cfg.wih) {
        if (tid < 64) {
          const int t = cfg.xt0 + s * cfg.xdt;
          xsh[tid] = cfg.xpk[((size_t)b * Tv + t) * 64 + tid];
        }
        __syncthreads();
      }
    }

    const uint4* H4 = (const uint4*)h16;
    float a00 = bias0, a01 = 0.f, a10 = bias1, a11 = 0.f;

#pragma unroll
    for (int c4 = 0; c4 < NRESP / 4; ++c4) {
      const uint4 hv = H4[c4];
      a00 = d2(hv.x, w0[4 * c4 + 0], a00);
      a01 = d2(hv.y, w0[4 * c4 + 1], a01);
      a10 = d2(hv.x, w1[4 * c4 + 0], a10);
      a11 = d2(hv.y, w1[4 * c4 + 1], a11);
      a00 = d2(hv.z, w0[4 * c4 + 2], a00);
      a01 = d2(hv.w, w0[4 * c4 + 3], a01);
      a10 = d2(hv.z, w1[4 * c4 + 2], a10);
      a11 = d2(hv.w, w1[4 * c4 + 3], a11);
    }
    if constexpr (NS4 > 0) {
#pragma unroll
      for (int u = 0; u < NS4; ++u) {
        const uint4 hv = H4[NRESP / 4 + u];
        const uint4 wv0 = ws0[u];
        const uint4 wv1 = ws1[u];
        a00 = d2(hv.x, wv0.x, a00);
        a01 = d2(hv.y, wv0.y, a01);
        a10 = d2(hv.x, wv1.x, a10);
        a11 = d2(hv.y, wv1.y, a11);
        a00 = d2(hv.z, wv0.z, a00);
        a01 = d2(hv.w, wv0.w, a01);
        a10 = d2(hv.z, wv1.z, a10);
        a11 = d2(hv.w, wv1.w, a11);
      }
    }
#pragma unroll
    for (int g = 0; g < 8; ++g) {
      const uint4 hv = H4[24 + g];
      const uint4 wv0 = wlds4[g * 1024 + r0];
      const uint4 wv1 = wlds4[g * 1024 + r1];
      a00 = d2(hv.x, wv0.x, a00);
      a01 = d2(hv.y, wv0.y, a01);
      a10 = d2(hv.x, wv1.x, a10);
      a11 = d2(hv.y, wv1.y, a11);
      a00 = d2(hv.z, wv0.z, a00);
      a01 = d2(hv.w, wv0.w, a01);
      a10 = d2(hv.z, wv1.z, a10);
      a11 = d2(hv.w, wv1.w, a11);
    }
    if constexpr (WIH) {
      if (cfg.wih) {
        const uint4* XS4 = (const uint4*)xsh;
#pragma unroll
        for (int u = 0; u < 16; ++u) {
          const uint4 xv = XS4[u];
          const uint4 wv0 = wi0[u];
          const uint4 wv1 = wi1[u];
          a00 = d2(xv.x, wv0.x, a00);
          a01 = d2(xv.y, wv0.y, a01);
          a10 = d2(xv.x, wv1.x, a10);
          a11 = d2(xv.y, wv1.y, a11);
          a00 = d2(xv.z, wv0.z, a00);
          a01 = d2(xv.w, wv0.w, a01);
          a10 = d2(xv.z, wv1.z, a10);
          a11 = d2(xv.w, wv1.w, a11);
        }
      }
    }

    gsm[r0] = a00 + a01 + xa0;
    gsm[r1] = a10 + a11 + xa1;
    __syncthreads();

    if (tid < 256) {
      const float gi = gsm[tid];
      const float gf = gsm[tid + 256];
      const float gg = gsm[tid + 512];
      const float go = gsm[tid + 768];
      const float cn = sigm(gf) * creg + sigm(gi) * tanh_(gg);
      const float hv = sigm(go) * tanh_(cn);
      creg = cn;
      const uint16_t hu = f2h(hv);
      h16[tid] = hu;
      if (histp && s < 1023) histp[(size_t)(s + 1) * 256 + tid] = hu;
    }
    __syncthreads();
  }

  if (cfg.hN && tid < 256) {
    cfg.hN[b * 256 + tid] = h2f(h16[tid]);
    cfg.cN[b * 256 + tid] = creg;
  }
}

// ---------------- output GEMM ----------------
__global__ __launch_bounds__(256) void k_out(const uint16_t* __restrict__ hist,
                                             const uint32_t* __restrict__ wlp,
                                             const float* __restrict__ lb,
                                             float* __restrict__ out, int outbase, int tsign) {
  const int b = blockIdx.y;
  const int t0 = blockIdx.x * 64;
  __shared__ __align__(16) uint32_t hq[64 * 128];
  const uint32_t* hsrc = (const uint32_t*)hist;
  for (int i = threadIdx.x; i < 64 * 128; i += 256) {
    hq[i] = hsrc[((size_t)b * 1024 + t0) * 128 + i];
  }
  __syncthreads();
  const int d = threadIdx.x & 127;
  const int th = threadIdx.x >> 7;
  float acc[32];
#pragma unroll
  for (int it = 0; it < 32; ++it) acc[it] = lb[d];
  const uint4* W4 = (const uint4*)(wlp + (size_t)d * 128);
  const uint4* HQ4 = (const uint4*)hq;
  for (int k2c = 0; k2c < 32; ++k2c) {
    const uint4 wv = W4[k2c];
#pragma unroll
    for (int it = 0; it < 32; ++it) {
      const int tl = th * 32 + it;
      const uint4 hv = HQ4[tl * 32 + k2c];
      acc[it] = d2(hv.x, wv.x, acc[it]);
      acc[it] = d2(hv.y, wv.y, acc[it]);
      acc[it] = d2(hv.z, wv.z, acc[it]);
      acc[it] = d2(hv.w, wv.w, acc[it]);
    }
  }
#pragma unroll
  for (int it = 0; it < 32; ++it) {
    const int tl = th * 32 + it;
    const int t = t0 + tl;
    const int tout = outbase + tsign * t;
    out[((size_t)b * Tv + tout) * Dv + d] = acc[it];
  }
}

// ---------------- host ----------------

extern "C" void kernel_launch(void* const* d_in, const int* in_sizes, int n_in,
                              void* d_out, int out_size, void* d_ws, size_t ws_size,
                              hipStream_t stream) {
  const float* x = (const float*)d_in[0];
  const float* e1_Wih = (const float*)d_in[1];
  const float* e1_Whh = (const float*)d_in[2];
  const float* e1_bih = (const float*)d_in[3];
  const float* e1_bhh = (const float*)d_in[4];
  const float* e2_Wih = (const float*)d_in[5];
  const float* e2_Whh = (const float*)d_in[6];
  const float* e2_bih = (const float*)d_in[7];
  const float* e2_bhh = (const float*)d_in[8];
  const float* d1_Wih = (const float*)d_in[9];
  const float* d1_Whh = (const float*)d_in[10];
  const float* d1_bih = (const float*)d_in[11];
  const float* d1_bhh = (const float*)d_in[12];
  const float* d2_Wih = (const float*)d_in[13];
  const float* d2_Whh = (const float*)d_in[14];
  const float* d2_bih = (const float*)d_in[15];
  const float* d2_bhh = (const float*)d_in[16];
  const float* l1_W = (const float*)d_in[17];
  const float* l1_b = (const float*)d_in[18];
  const float* l2_W = (const float*)d_in[19];
  const float* l2_b = (const float*)d_in[20];

  uint8_t* wsb = (uint8_t*)d_ws;
  size_t off = 0;
  auto take = [&](size_t n) -> void* {
    void* pp = wsb + off;
    off += (n + 255) & ~(size_t)255;
    return pp;
  };
  uint32_t* xpk = (uint32_t*)take((size_t)Bv * Tv * 64 * 4);
  uint16_t* hist1 = (uint16_t*)take((size_t)Bv * T1v * Hv * 2);
  uint16_t* hist2 = (uint16_t*)take((size_t)Bv * T1v * Hv * 2);
  struct WSet {
    uint32_t *wAll, *wLg, *wStr, *wih;
    float* bias;
    uint32_t *wSt, *wLds, *bpk;
  };
  auto take_wset = [&](bool with_ih) -> WSet {
    WSet w;
    w.wAll = (uint32_t*)take(128 * 1024 * 4);
    w.wLg = (uint32_t*)take(8 * 1024 * 16);
    w.wStr = (uint32_t*)take(1024 * 48 * 4);
    w.wih = with_ih ? (uint32_t*)take(1024 * 64 * 4) : nullptr;
    w.bias = (float*)take(1024 * 4);
    w.wSt = (uint32_t*)take(48 * 512 * 16);
    w.wLds = (uint32_t*)take(16 * 512 * 16);
    w.bpk = (uint32_t*)take(128 * 16);
    return w;
  };
  WSet we1 = take_wset(true);
  WSet we2 = take_wset(true);
  WSet wd1 = take_wset(false);
  WSet wd2 = take_wset(false);
  float* wd32 = (float*)take(1024 * 256 * 4);
  uint32_t* wl1p = (uint32_t*)take(128 * 128 * 4);
  uint32_t* wl2p = (uint32_t*)take(128 * 128 * 4);
  float* h1 = (float*)take(64 * 256 * 4);
  float* c1 = (float*)take(64 * 256 * 4);
  float* h2 = (float*)take(64 * 256 * 4);
  float* c2 = (float*)take(64 * 256 * 4);
  uint16_t* xp = (uint16_t*)take((size_t)Bv * T1v * 1024 * 2);  // shared e1/e2
  const bool use_xp = ws_size >= off;

  // ---- pick variant ----
  // 0: k_rnnU<6,1,1>  1: k_rnnU<6,0,2>  2: k_rnnU<4,2,2>  3: k_rnn5<96>  4: k_rnn5<80>
  int variant = 4;
  {
    hipFuncAttributes fa;
    auto spillfree = [&](const void* f) {
      return hipFuncGetAttributes(&fa, f) == hipSuccess && fa.localSizeBytes == 0;
    };
    if (use_xp) {
      if (spillfree(reinterpret_cast<const void*>(&k_rnnU<6, 1, 1>))) variant = 0;
      else if (spillfree(reinterpret_cast<const void*>(&k_rnnU<6, 0, 2>))) variant = 1;
      else if (spillfree(reinterpret_cast<const void*>(&k_rnnU<4, 2, 2>))) variant = 2;
      else if (spillfree(reinterpret_cast<const void*>(&k_rnn5<96, false>))) variant = 3;
    } else {
      if (spillfree(reinterpret_cast<const void*>(&k_rnn5<96, true>))) variant = 3;
    }
  }

  // ---- prep ----
  k_pack_x<<<(Bv * Tv * 64) / 256, 256, 0, stream>>>(x, xpk);
  k_pack_w<<<512, 256, 0, stream>>>(e1_Whh, we1.wAll, we1.wLg, we1.wStr);
  k_pack_w2<<<512, 256, 0, stream>>>(e1_Whh, we1.wSt, we1.wLds);
  k_pack_wih<<<256, 256, 0, stream>>>(e1_Wih, we1.wih);
  k_bias2<<<4, 256, 0, stream>>>(e1_bih, e1_bhh, we1.bias);
  k_bias_pack<<<1, 128, 0, stream>>>(we1.bias, we1.bpk);
  k_pack_w<<<512, 256, 0, stream>>>(e2_Whh, we2.wAll, we2.wLg, we2.wStr);
  k_pack_w2<<<512, 256, 0, stream>>>(e2_Whh, we2.wSt, we2.wLds);
  k_pack_wih<<<256, 256, 0, stream>>>(e2_Wih, we2.wih);
  k_bias2<<<4, 256, 0, stream>>>(e2_bih, e2_bhh, we2.bias);
  k_bias_pack<<<1, 128, 0, stream>>>(we2.bias, we2.bpk);
  k_dec_combine<<<1024, 256, 0, stream>>>(d1_Whh, d1_Wih, d1_bih, d1_bhh, l1_W, l1_b, wd32, wd1.bias);
  k_pack_w<<<512, 256, 0, stream>>>(wd32, wd1.wAll, wd1.wLg, wd1.wStr);
  k_pack_w2<<<512, 256, 0, stream>>>(wd32, wd1.wSt, wd1.wLds);
  k_bias_pack<<<1, 128, 0, stream>>>(wd1.bias, wd1.bpk);
  k_dec_combine<<<1024, 256, 0, stream>>>(d2_Whh, d2_Wih, d2_bih, d2_bhh, l2_W, l2_b, wd32, wd2.bias);
  k_pack_w<<<512, 256, 0, stream>>>(wd32, wd2.wAll, wd2.wLg, wd2.wStr);
  k_pack_w2<<<512, 256, 0, stream>>>(wd32, wd2.wSt, wd2.wLds);
  k_bias_pack<<<1, 128, 0, stream>>>(wd2.bias, wd2.bpk);
  k_pack_wl<<<64, 256, 0, stream>>>(l1_W, wl1p);
  k_pack_wl<<<64, 256, 0, stream>>>(l2_W, wl2p);

  if (variant <= 2) {
    auto launch_u = [&](int grid, CfgU a, CfgU b2, int nA) {
      if (variant == 0)      k_rnnU<6, 1, 1><<<grid, 512, 0, stream>>>(a, b2, nA);
      else if (variant == 1) k_rnnU<6, 0, 2><<<grid, 512, 0, stream>>>(a, b2, nA);
      else                   k_rnnU<4, 2, 2><<<grid, 512, 0, stream>>>(a, b2, nA);
    };
    k_xp_gemm<0><<<dim3(4, 32, 64), 256, 0, stream>>>(xpk, we1.wih, xp, 1023, -1);
    CfgU e1c{(const uint4*)we1.wSt, (const uint4*)we1.wLds, (const uint4*)we1.bpk,
             (const uint4*)xp, nullptr, nullptr, h1, c1, nullptr};
    launch_u(64, e1c, e1c, 64);

    k_xp_gemm<0><<<dim3(4, 32, 64), 256, 0, stream>>>(xpk, we2.wih, xp, 1024, 1);
    CfgU e2c{(const uint4*)we2.wSt, (const uint4*)we2.wLds, (const uint4*)we2.bpk,
             (const uint4*)xp, h1, c1, h2, c2, nullptr};
    CfgU d1c{(const uint4*)wd1.wSt, (const uint4*)wd1.wLds, (const uint4*)wd1.bpk,
             nullptr, h1, c1, nullptr, nullptr, hist1};
    launch_u(128, e2c, d1c, 64);

    CfgU d2c{(const uint4*)wd2.wSt, (const uint4*)wd2.wLds, (const uint4*)wd2.bpk,
             nullptr, h2, c2, nullptr, nullptr, hist2};
    launch_u(64, d2c, d2c, 64);
  } else {
    auto launch_old = [&](int grid, ChainCfg a, ChainCfg b2, int nA) {
      if (use_xp) {
        if (variant == 3) k_rnn5<96, false><<<grid, 512, 0, stream>>>(a, b2, nA);
        else              k_rnn5<80, false><<<grid, 512, 0, stream>>>(a, b2, nA);
      } else {
        if (variant == 3) k_rnn5<96, true><<<grid, 512, 0, stream>>>(a, b2, nA);
        else              k_rnn5<80, true><<<grid, 512, 0, stream>>>(a, b2, nA);
      }
    };
    if (use_xp) k_xp_gemm<1><<<dim3(4, 32, 64), 256, 0, stream>>>(xpk, we1.wih, xp, 1023, -1);
    ChainCfg e1c{we1.wAll, (const uint4*)we1.wLg, we1.wStr, use_xp ? nullptr : we1.wih,
                 use_xp ? nullptr : xpk, use_xp ? xp : nullptr, we1.bias,
                 nullptr, nullptr, h1, c1, nullptr, 1023, -1};
    launch_old(64, e1c, e1c, 64);

    if (use_xp) k_xp_gemm<1><<<dim3(4, 32, 64), 256, 0, stream>>>(xpk, we2.wih, xp, 1024, 1);
    ChainCfg e2c{we2.wAll, (const uint4*)we2.wLg, we2.wStr, use_xp ? nullptr : we2.wih,
                 use_xp ? nullptr : xpk, use_xp ? xp : nullptr, we2.bias,
                 h1, c1, h2, c2, nullptr, 1024, 1};
    ChainCfg d1c{wd1.wAll, (const uint4*)wd1.wLg, wd1.wStr, nullptr, nullptr, nullptr,
                 wd1.bias, h1, c1, nullptr, nullptr, hist1, 0, 0};
    launch_old(128, e2c, d1c, 64);

    ChainCfg d2c{wd2.wAll, (const uint4*)wd2.wLg, wd2.wStr, nullptr, nullptr, nullptr,
                 wd2.bias, h2, c2, nullptr, nullptr, hist2, 0, 0};
    launch_old(64, d2c, d2c, 64);
  }

  // ---- outputs ----
  k_out<<<dim3(16, 64), 256, 0, stream>>>(hist1, wl1p, l1_b, (float*)d_out, 0, 1);
  k_out<<<dim3(16, 64), 256, 0, stream>>>(hist2, wl2p, l2_b, (float*)d_out, 2047, -1);
}

// Round 8
// 7170.893 us; speedup vs baseline: 1.0179x; 1.0179x over previous
//
#include <hip/hip_runtime.h>
#include <stdint.h>

#define Bv 64
#define Tv 2048
#define T1v 1024
#define Dv 128
#define Hv 256

typedef _Float16 h2_t __attribute__((ext_vector_type(2)));

template <int V> struct IC { static constexpr int v = V; };

__device__ inline float d2(uint32_t hp, uint32_t wp, float acc) {
#if __has_builtin(__builtin_amdgcn_fdot2)
  return __builtin_amdgcn_fdot2(__builtin_bit_cast(h2_t, hp),
                                __builtin_bit_cast(h2_t, wp), acc, false);
#else
  float out;
  asm("v_dot2_f32_f16 %0, %1, %2, %3" : "=v"(out) : "v"(hp), "v"(wp), "v"(acc));
  return out;
#endif
}

__device__ inline uint16_t f2h(float x) {
  _Float16 h = (_Float16)x;
  return __builtin_bit_cast(uint16_t, h);
}
__device__ inline float h2f(uint16_t u) {
  return (float)__builtin_bit_cast(_Float16, u);
}
__device__ inline uint32_t packpair(float a, float b) {
  return (uint32_t)f2h(a) | ((uint32_t)f2h(b) << 16);
}
__device__ inline float unpk(uint32_t u, int hi) {
  return h2f((uint16_t)(hi ? (u >> 16) : (u & 0xffff)));
}
__device__ inline float sigm(float x) { return 1.f / (1.f + __expf(-x)); }
__device__ inline float tanh_(float x) { return 2.f / (1.f + __expf(-2.f * x)) - 1.f; }

// butterfly sum over the 4 lanes of a quad (quad_perm: selector-explicit, proven R6)
__device__ inline float qsum4(float v) {
  int t = __builtin_amdgcn_update_dpp(0, __float_as_int(v), 0xB1, 0xF, 0xF, true);
  v += __int_as_float(t);
  t = __builtin_amdgcn_update_dpp(0, __float_as_int(v), 0x4E, 0xF, 0xF, true);
  return v + __int_as_float(t);
}

// rotate a uint4 across the 4 same-q lanes (lanes l, l+4, l+8, l+12) via DPP row_ror
template <int CTRL>
__device__ inline uint4 dpp_rot4(uint4 v) {
  uint4 r;
  r.x = (uint32_t)__builtin_amdgcn_update_dpp(0, (int)v.x, CTRL, 0xF, 0xF, true);
  r.y = (uint32_t)__builtin_amdgcn_update_dpp(0, (int)v.y, CTRL, 0xF, 0xF, true);
  r.z = (uint32_t)__builtin_amdgcn_update_dpp(0, (int)v.z, CTRL, 0xF, 0xF, true);
  r.w = (uint32_t)__builtin_amdgcn_update_dpp(0, (int)v.w, CTRL, 0xF, 0xF, true);
  return r;
}

// ---------------- DPP direction probe ----------------
// After ror:4, lane 0 holds lane 4's value (DIR=0, "plus": dst[n]=src[(n+4)&15])
// or lane 12's value (DIR=1, "minus": dst[n]=src[(n-4)&15]).
__global__ void k_dpp_probe(uint32_t* flag) {
  uint32_t v = threadIdx.x;
  uint32_t r = (uint32_t)__builtin_amdgcn_update_dpp(0, (int)v, 0x124, 0xF, 0xF, true);
  if (threadIdx.x == 0) *flag = (r == 4u) ? 0u : 1u;
}

// ---------------- prep kernels ----------------

__global__ void k_pack_x(const float* __restrict__ x, uint32_t* __restrict__ xpk) {
  int idx = blockIdx.x * 256 + threadIdx.x;  // B*T*64
  const float2* x2 = (const float2*)x;
  float2 v = x2[idx];
  xpk[idx] = packpair(v.x, v.y);
}

// rnn5 fallback layout
__global__ void k_pack_w(const float* __restrict__ src, uint32_t* __restrict__ wAll,
                         uint32_t* __restrict__ wLg, uint32_t* __restrict__ wStr) {
  int idx = blockIdx.x * 256 + threadIdx.x;  // 1024*128
  int row = idx >> 7, k2 = idx & 127;
  uint32_t pr = packpair(src[row * 256 + 2 * k2], src[row * 256 + 2 * k2 + 1]);
  wAll[k2 * 1024 + row] = pr;
  if (k2 >= 96) {
    int g = (k2 - 96) >> 2, qq = (k2 - 96) & 3;
    wLg[(g * 1024 + row) * 4 + qq] = pr;
  }
  if (k2 >= 48 && k2 < 96) wStr[row * 48 + (k2 - 48)] = pr;
}

// U6 (R6-proven) layout
__global__ void k_pack_w2(const float* __restrict__ src, uint32_t* __restrict__ wReg,
                          uint32_t* __restrict__ wLds) {
  int idx = blockIdx.x * 256 + threadIdx.x;  // 1024*128
  int r = idx >> 7, k2 = idx & 127;
  uint32_t pr = packpair(src[r * 256 + 2 * k2], src[r * 256 + 2 * k2 + 1]);
  int gate = r >> 8, u = r & 255;
  int u_hi = u >> 7, jb = u & 127;
  int q = k2 >> 5, kk = k2 & 31;
  int tid = jb * 4 + q;
  int ri = u_hi * 4 + gate;
  int cc = kk >> 2, c = kk & 3;
  if (cc < 6) {
    wReg[((ri * 6 + cc) * 512 + tid) * 4 + c] = pr;
  } else {
    wLds[((ri * 2 + (cc - 6)) * 512 + tid) * 4 + c] = pr;
  }
}

// U2 layout, "plus"-direction slot map: slot = 2*(((cc>>1) - jbm)&3) + (cc&1)
// (kernel compensates at runtime if probe reports minus-direction)
__global__ void k_pack_w3(const float* __restrict__ src, uint32_t* __restrict__ wReg,
                          uint32_t* __restrict__ wStr, uint32_t* __restrict__ wLds,
                          int R, int S) {
  int idx = blockIdx.x * 256 + threadIdx.x;  // 1024*128
  int r = idx >> 7, k2 = idx & 127;
  uint32_t pr = packpair(src[r * 256 + 2 * k2], src[r * 256 + 2 * k2 + 1]);
  int gate = r >> 8, u2 = r & 255;
  int u_hi = u2 >> 7, jb = u2 & 127;
  int q = k2 >> 5, kk = k2 & 31;
  int cc = kk >> 2, c = kk & 3;
  int tid = jb * 4 + q;
  int ri = u_hi * 4 + gate;
  int jbm = jb & 3;
  int slot = 2 * (((cc >> 1) - jbm) & 3) + (cc & 1);
  if (slot < R) {
    wReg[((ri * R + slot) * 512 + tid) * 4 + c] = pr;
  } else if (slot < R + S) {
    int j = slot - R;
    size_t o = ((size_t)(ri * S + j) * 512 + tid) * 4 + c;
    wStr[o] = pr;
    wStr[(size_t)8 * S * 512 * 4 + o] = pr;  // second image (anti-LICM)
  } else {
    int L = 8 - R - S;
    int l = slot - R - S;
    wLds[((ri * L + l) * 512 + tid) * 4 + c] = pr;
  }
}

// bias packed f16
__global__ void k_bias_pack(const float* __restrict__ b32, uint32_t* __restrict__ bpk) {
  int jb = threadIdx.x;  // 128
  uint32_t w[4];
#pragma unroll
  for (int wi = 0; wi < 4; ++wi) {
    int ri0 = 2 * wi, ri1 = 2 * wi + 1;
    int row0 = (ri0 & 3) * 256 + jb + 128 * (ri0 >> 2);
    int row1 = (ri1 & 3) * 256 + jb + 128 * (ri1 >> 2);
    w[wi] = packpair(b32[row0], b32[row1]);
  }
  ((uint4*)bpk)[jb] = make_uint4(w[0], w[1], w[2], w[3]);
}

__global__ void k_pack_wih(const float* __restrict__ Wih, uint32_t* __restrict__ wihp) {
  int idx = blockIdx.x * 256 + threadIdx.x;  // 1024*64
  int row = idx >> 6, k2 = idx & 63;
  wihp[row * 64 + k2] = packpair(Wih[row * 128 + 2 * k2], Wih[row * 128 + 2 * k2 + 1]);
}

__global__ void k_bias2(const float* __restrict__ bih, const float* __restrict__ bhh,
                        float* __restrict__ bias) {
  int i = blockIdx.x * 256 + threadIdx.x;
  if (i < 1024) bias[i] = bih[i] + bhh[i];
}

__global__ void k_dec_combine(const float* __restrict__ Whh, const float* __restrict__ Wih,
                              const float* __restrict__ bih, const float* __restrict__ bhh,
                              const float* __restrict__ lW, const float* __restrict__ lb,
                              float* __restrict__ wd, float* __restrict__ bias) {
  int j = blockIdx.x;
  int k = threadIdx.x;
  __shared__ float wr[128];
  if (k < 128) wr[k] = Wih[j * 128 + k];
  __syncthreads();
  float acc = Whh[j * 256 + k];
  for (int d = 0; d < 128; ++d) acc += wr[d] * lW[d * 256 + k];
  wd[j * 256 + k] = acc;
  if (k == 0) {
    float s = bih[j] + bhh[j];
    for (int d = 0; d < 128; ++d) s += wr[d] * lb[d];
    bias[j] = s;
  }
}

__global__ void k_pack_wl(const float* __restrict__ lW, uint32_t* __restrict__ wlp) {
  int idx = blockIdx.x * 256 + threadIdx.x;  // 128*128
  int d = idx >> 7, k2 = idx & 127;
  wlp[d * 128 + k2] = packpair(lW[d * 256 + 2 * k2], lW[d * 256 + 2 * k2 + 1]);
}

// Xp precompute. LAY=0: xp[((b*1024+s)*128+jb)*8 + ri]; LAY=1: xp[(b*1024+s)*1024 + r]
template <int LAY>
__global__ __launch_bounds__(256) void k_xp_gemm(const uint32_t* __restrict__ xpk,
                                                 const uint32_t* __restrict__ wihp,
                                                 uint16_t* __restrict__ xp, int xt0, int xdt) {
  const int b = blockIdx.z;
  const int s0 = blockIdx.y * 32;
  const int r = blockIdx.x * 256 + threadIdx.x;
  uint32_t wreg[64];
#pragma unroll
  for (int k = 0; k < 64; ++k) wreg[k] = wihp[r * 64 + k];
  const int gate = r >> 8, u = r & 255;
  const int u_hi = u >> 7, jb = u & 127;
  const int ri = u_hi * 4 + gate;
  for (int sl = 0; sl < 32; ++sl) {
    const int s = s0 + sl;
    const int t = xt0 + s * xdt;
    const uint32_t* __restrict__ xrow = xpk + ((size_t)b * Tv + t) * 64;
    float a0 = 0.f, a1 = 0.f;
#pragma unroll
    for (int k = 0; k < 64; k += 2) {
      a0 = d2(xrow[k], wreg[k], a0);
      a1 = d2(xrow[k + 1], wreg[k + 1], a1);
    }
    uint16_t v = f2h(a0 + a1);
    if (LAY == 0)
      xp[(((size_t)b * T1v + s) * 128 + jb) * 8 + ri] = v;
    else
      xp[((size_t)b * T1v + s) * 1024 + r] = v;
  }
}

// ---------------- unified config ----------------

struct CfgU {
  const uint4* wA;   // register-resident weight image
  const uint4* wB;   // streamed weight image (2 copies) or null
  const uint4* wC;   // LDS weight image
  const uint4* bpk;  // [128]
  const uint4* xps;  // [B][1024][128] or null
  const float* h0;
  const float* c0;
  float* hN;
  float* cN;
  uint16_t* hist;        // [B][1024][256] or null
  const uint32_t* dir;   // DPP direction flag (U2 only)
};

// ---------------- U2: DPP h-gather + L2 stream, direction-proof ----------------
template <int R, int S>
__global__ void __launch_bounds__(512)
__attribute__((amdgpu_waves_per_eu(2, 2)))
k_rnnU2(CfgU cA, CfgU cB, int nA) {
  constexpr int L = 8 - R - S;
  __shared__ __align__(16) uint4 wldsM[L * 8 * 512];
  __shared__ __align__(16) uint16_t hbuf[2][4][80];

  const bool isA = (int)blockIdx.x < nA;
  const CfgU cfg = isA ? cA : cB;
  const int b = isA ? (int)blockIdx.x : ((int)blockIdx.x - nA);
  const int tid = threadIdx.x;
  const int q = tid & 3, jb = tid >> 2;
  const int jbm = jb & 3;

  const uint32_t dirv = __builtin_amdgcn_readfirstlane(*cfg.dir);

#pragma unroll
  for (int i = 0; i < 8 * L; ++i) wldsM[i * 512 + tid] = cfg.wC[i * 512 + tid];

  uint4 wr[8][R];
#pragma unroll
  for (int ri = 0; ri < 8; ++ri)
#pragma unroll
    for (int u = 0; u < R; ++u) wr[ri][u] = cfg.wA[(ri * R + u) * 512 + tid];

  const uint4 bp = cfg.bpk[jb];
  float c0r = cfg.c0 ? cfg.c0[b * 256 + jb] : 0.f;
  float c1r = cfg.c0 ? cfg.c0[b * 256 + jb + 128] : 0.f;

  uint16_t* histp = cfg.hist ? cfg.hist + (size_t)b * 1024 * 256 : nullptr;
  if (q == 0) {
    float h00 = cfg.h0 ? cfg.h0[b * 256 + jb] : 0.f;
    float h01 = cfg.h0 ? cfg.h0[b * 256 + jb + 128] : 0.f;
    uint16_t u0 = f2h(h00), u1 = f2h(h01);
    hbuf[0][jb >> 6][jb & 63] = u0;
    hbuf[0][2 + (jb >> 6)][jb & 63] = u1;
    if (histp) {
      histp[jb] = u0;
      histp[jb + 128] = u1;
    }
  }
  const uint4* xps4 = cfg.xps ? cfg.xps + (size_t)b * 1024 * 128 + jb : nullptr;

  __syncthreads();

  int cur = 0;

  auto run = [&](auto DIRC) {
    constexpr int DIR = decltype(DIRC)::v;
    for (int s = 0; s < 1024; ++s) {
      uint4 xq = make_uint4(0, 0, 0, 0);
      if (xps4) xq = xps4[(size_t)s * 128];

      const uint4* wS = cfg.wB + ((s & 1) ? (size_t)(8 * S * 512) : (size_t)0);
      uint4 sv[8 * S];
#pragma unroll
      for (int ri = 0; ri < 8; ++ri)
#pragma unroll
        for (int j = 0; j < S; ++j) sv[ri * S + j] = wS[(ri * S + j) * 512 + tid];

      const uint4* Hq4 = (const uint4*)(&hbuf[cur][q][0]);
      const uint4 hh0 = Hq4[2 * jbm];
      const uint4 hh1 = Hq4[2 * jbm + 1];

      float acc[8];
#pragma unroll
      for (int ri = 0; ri < 8; ++ri) acc[ri] = 0.f;

#pragma unroll
      for (int d = 0; d < 4; ++d) {
        uint4 h0 = hh0, h1 = hh1;
        if (d == 1) { h0 = dpp_rot4<0x124>(hh0); h1 = dpp_rot4<0x124>(hh1); }
        if (d == 2) { h0 = dpp_rot4<0x128>(hh0); h1 = dpp_rot4<0x128>(hh1); }
        if (d == 3) { h0 = dpp_rot4<0x12C>(hh0); h1 = dpp_rot4<0x12C>(hh1); }
#pragma unroll
        for (int k = 0; k < 2; ++k) {
          // plus-dir: held chunk-group = (jbm+d)&3 -> slot 2d+k
          // minus-dir: held chunk-group = (jbm-d)&3 -> slot 2*((4-d)&3)+k
          const int u = (DIR == 0) ? (2 * d + k) : (2 * ((4 - d) & 3) + k);
          const uint4 hv = k ? h1 : h0;
#pragma unroll
          for (int ri = 0; ri < 8; ++ri) {
            uint4 wv;
            if (u < R) wv = wr[ri][u];
            else if (u < R + S) wv = sv[ri * S + (u - R)];
            else wv = wldsM[(ri * L + (u - R - S)) * 512 + tid];
            acc[ri] = d2(hv.x, wv.x, acc[ri]);
            acc[ri] = d2(hv.y, wv.y, acc[ri]);
            acc[ri] = d2(hv.z, wv.z, acc[ri]);
            acc[ri] = d2(hv.w, wv.w, acc[ri]);
          }
        }
      }

#pragma unroll
      for (int ri = 0; ri < 8; ++ri) acc[ri] = qsum4(acc[ri]);

      acc[0] += unpk(bp.x, 0) + unpk(xq.x, 0);
      acc[1] += unpk(bp.x, 1) + unpk(xq.x, 1);
      acc[2] += unpk(bp.y, 0) + unpk(xq.y, 0);
      acc[3] += unpk(bp.y, 1) + unpk(xq.y, 1);
      acc[4] += unpk(bp.z, 0) + unpk(xq.z, 0);
      acc[5] += unpk(bp.z, 1) + unpk(xq.z, 1);
      acc[6] += unpk(bp.w, 0) + unpk(xq.w, 0);
      acc[7] += unpk(bp.w, 1) + unpk(xq.w, 1);

      const float cn0 = sigm(acc[1]) * c0r + sigm(acc[0]) * tanh_(acc[2]);
      const float h0v = sigm(acc[3]) * tanh_(cn0);
      c0r = cn0;
      const float cn1 = sigm(acc[5]) * c1r + sigm(acc[4]) * tanh_(acc[6]);
      const float h1v = sigm(acc[7]) * tanh_(cn1);
      c1r = cn1;

      if (q == 0) {
        const uint16_t hu0 = f2h(h0v), hu1 = f2h(h1v);
        hbuf[cur ^ 1][jb >> 6][jb & 63] = hu0;
        hbuf[cur ^ 1][2 + (jb >> 6)][jb & 63] = hu1;
        if (histp && s < 1023) {
          histp[(size_t)(s + 1) * 256 + jb] = hu0;
          histp[(size_t)(s + 1) * 256 + jb + 128] = hu1;
        }
      }
      __syncthreads();
      cur ^= 1;
    }
  };

  if (dirv == 0) run(IC<0>{});
  else           run(IC<1>{});

  if (cfg.hN && q == 0) {
    cfg.hN[b * 256 + jb] = h2f(hbuf[cur][jb >> 6][jb & 63]);
    cfg.hN[b * 256 + jb + 128] = h2f(hbuf[cur][2 + (jb >> 6)][jb & 63]);
    cfg.cN[b * 256 + jb] = c0r;
    cfg.cN[b * 256 + jb + 128] = c1r;
  }
}

// ---------------- U6 (R6-proven fallback) ----------------
__global__ void __launch_bounds__(512)
__attribute__((amdgpu_waves_per_eu(2, 2)))
k_rnnU6(CfgU cA, CfgU cB, int nA) {
  __shared__ __align__(16) uint4 wldsM[2 * 8 * 512];
  __shared__ __align__(16) uint16_t hbuf[2][4][72];

  const bool isA = (int)blockIdx.x < nA;
  const CfgU cfg = isA ? cA : cB;
  const int b = isA ? (int)blockIdx.x : ((int)blockIdx.x - nA);
  const int tid = threadIdx.x;
  const int q = tid & 3, jb = tid >> 2;

#pragma unroll
  for (int i = 0; i < 16; ++i) wldsM[i * 512 + tid] = cfg.wC[i * 512 + tid];

  uint4 wr[8][6];
#pragma unroll
  for (int ri = 0; ri < 8; ++ri)
#pragma unroll
    for (int cc = 0; cc < 6; ++cc) wr[ri][cc] = cfg.wA[(ri * 6 + cc) * 512 + tid];

  const uint4 bp = cfg.bpk[jb];
  float c0r = cfg.c0 ? cfg.c0[b * 256 + jb] : 0.f;
  float c1r = cfg.c0 ? cfg.c0[b * 256 + jb + 128] : 0.f;

  uint16_t* histp = cfg.hist ? cfg.hist + (size_t)b * 1024 * 256 : nullptr;
  if (q == 0) {
    float h00 = cfg.h0 ? cfg.h0[b * 256 + jb] : 0.f;
    float h01 = cfg.h0 ? cfg.h0[b * 256 + jb + 128] : 0.f;
    uint16_t u0 = f2h(h00), u1 = f2h(h01);
    hbuf[0][jb >> 6][jb & 63] = u0;
    hbuf[0][2 + (jb >> 6)][jb & 63] = u1;
    if (histp) {
      histp[jb] = u0;
      histp[jb + 128] = u1;
    }
  }
  const uint4* xps4 = cfg.xps ? cfg.xps + (size_t)b * 1024 * 128 + jb : nullptr;

  __syncthreads();

  int cur = 0;
  for (int s = 0; s < 1024; ++s) {
    uint4 xq = make_uint4(0, 0, 0, 0);
    if (xps4) xq = xps4[(size_t)s * 128];
    const uint4* Hq = (const uint4*)(&hbuf[cur][q][0]);

    float acc[8];
#pragma unroll
    for (int ri = 0; ri < 8; ++ri) acc[ri] = 0.f;

#pragma unroll
    for (int cc = 0; cc < 6; ++cc) {
      const uint4 hv = Hq[cc];
#pragma unroll
      for (int ri = 0; ri < 8; ++ri) {
        acc[ri] = d2(hv.x, wr[ri][cc].x, acc[ri]);
        acc[ri] = d2(hv.y, wr[ri][cc].y, acc[ri]);
        acc[ri] = d2(hv.z, wr[ri][cc].z, acc[ri]);
        acc[ri] = d2(hv.w, wr[ri][cc].w, acc[ri]);
      }
    }
#pragma unroll
    for (int l = 0; l < 2; ++l) {
      const uint4 hv = Hq[6 + l];
#pragma unroll
      for (int ri = 0; ri < 8; ++ri) {
        const uint4 wv = wldsM[(ri * 2 + l) * 512 + tid];
        acc[ri] = d2(hv.x, wv.x, acc[ri]);
        acc[ri] = d2(hv.y, wv.y, acc[ri]);
        acc[ri] = d2(hv.z, wv.z, acc[ri]);
        acc[ri] = d2(hv.w, wv.w, acc[ri]);
      }
    }

#pragma unroll
    for (int ri = 0; ri < 8; ++ri) acc[ri] = qsum4(acc[ri]);

    acc[0] += unpk(bp.x, 0) + unpk(xq.x, 0);
    acc[1] += unpk(bp.x, 1) + unpk(xq.x, 1);
    acc[2] += unpk(bp.y, 0) + unpk(xq.y, 0);
    acc[3] += unpk(bp.y, 1) + unpk(xq.y, 1);
    acc[4] += unpk(bp.z, 0) + unpk(xq.z, 0);
    acc[5] += unpk(bp.z, 1) + unpk(xq.z, 1);
    acc[6] += unpk(bp.w, 0) + unpk(xq.w, 0);
    acc[7] += unpk(bp.w, 1) + unpk(xq.w, 1);

    const float cn0 = sigm(acc[1]) * c0r + sigm(acc[0]) * tanh_(acc[2]);
    const float h0v = sigm(acc[3]) * tanh_(cn0);
    c0r = cn0;
    const float cn1 = sigm(acc[5]) * c1r + sigm(acc[4]) * tanh_(acc[6]);
    const float h1v = sigm(acc[7]) * tanh_(cn1);
    c1r = cn1;

    if (q == 0) {
      const uint16_t hu0 = f2h(h0v), hu1 = f2h(h1v);
      hbuf[cur ^ 1][jb >> 6][jb & 63] = hu0;
      hbuf[cur ^ 1][2 + (jb >> 6)][jb & 63] = hu1;
      if (histp && s < 1023) {
        histp[(size_t)(s + 1) * 256 + jb] = hu0;
        histp[(size_t)(s + 1) * 256 + jb + 128] = hu1;
      }
    }
    __syncthreads();
    cur ^= 1;
  }

  if (cfg.hN && q == 0) {
    cfg.hN[b * 256 + jb] = h2f(hbuf[cur][jb >> 6][jb & 63]);
    cfg.hN[b * 256 + jb + 128] = h2f(hbuf[cur][2 + (jb >> 6)][jb & 63]);
    cfg.cN[b * 256 + jb] = c0r;
    cfg.cN[b * 256 + jb + 128] = c1r;
  }
}

// ---------------- rnn5 (R4-proven deep fallback) ----------------

struct ChainCfg {
  const uint32_t* wAll;
  const uint4* wLg;
  const uint32_t* wStr;
  const uint32_t* wih;
  const uint32_t* xpk;
  const uint16_t* xps;
  const float* bias;
  const float* h0;
  const float* c0;
  float* hN;
  float* cN;
  uint16_t* hist;
  int xt0, xdt;
};

template <int NRESP, bool WIH>
__global__ void __launch_bounds__(512)
__attribute__((amdgpu_waves_per_eu(2, 2)))
k_rnn5(ChainCfg cA, ChainCfg cB, int nA) {
  __shared__ __align__(16) uint4 wlds4[8 * 1024];
  __shared__ float gsm[1024];
  __shared__ __align__(16) uint16_t h16[256];
  __shared__ __align__(16) uint32_t xsh[64];

  const bool isA = (int)blockIdx.x < nA;
  const ChainCfg cfg = isA ? cA : cB;
  const int b = isA ? (int)blockIdx.x : ((int)blockIdx.x - nA);
  const int tid = threadIdx.x;
  const int r0 = tid, r1 = tid + 512;

#pragma unroll
  for (int i = 0; i < 16; ++i) wlds4[i * 512 + tid] = cfg.wLg[i * 512 + tid];

  uint16_t* histp = cfg.hist ? cfg.hist + (size_t)b * 1024 * 256 : nullptr;

  float creg = 0.f;
  if (tid < 256) {
    float h0v = cfg.h0 ? cfg.h0[b * 256 + tid] : 0.f;
    creg = cfg.c0 ? cfg.c0[b * 256 + tid] : 0.f;
    uint16_t hu = f2h(h0v);
    h16[tid] = hu;
    if (histp) histp[tid] = hu;
  }

  uint32_t w0[NRESP], w1[NRESP];
#pragma unroll
  for (int k = 0; k < NRESP; ++k) w0[k] = cfg.wAll[k * 1024 + r0];
#pragma unroll
  for (int k = 0; k < NRESP; ++k) w1[k] = cfg.wAll[k * 1024 + r1];
  const float bias0 = cfg.bias[r0];
  const float bias1 = cfg.bias[r1];

  constexpr int NS4 = (96 - NRESP) / 4;
  const uint4* ws0 = (const uint4*)(cfg.wStr + (size_t)r0 * 48 + (NRESP - 48));
  const uint4* ws1 = (const uint4*)(cfg.wStr + (size_t)r1 * 48 + (NRESP - 48));
  const uint4* wi0 = cfg.wih ? (const uint4*)(cfg.wih + (size_t)r0 * 64) : nullptr;
  const uint4* wi1 = cfg.wih ? (const uint4*)(cfg.wih + (size_t)r1 * 64) : nullptr;
  const bool hasx = cfg.xps != nullptr;

  __syncthreads();

  for (int s = 0; s < 1024; ++s) {
    float xa0 = 0.f, xa1 = 0.f;
    if (hasx) {
      size_t xb = ((size_t)b * 1024 + s) * 1024;
      xa0 = h2f(cfg.xps[xb + r0]);
      xa1 = h2f(cfg.xps[xb + r1]);
    }
    if constexpr (WIH) {
      if (cfg.wih) {
        if (tid < 64) {
          const int t = cfg.xt0 + s * cfg.xdt;
          xsh[tid] = cfg.xpk[((size_t)b * Tv + t) * 64 + tid];
        }
        __syncthreads();
      }
    }

    const uint4* H4 = (const uint4*)h16;
    float a00 = bias0, a01 = 0.f, a10 = bias1, a11 = 0.f;

#pragma unroll
    for (int c4 = 0; c4 < NRESP / 4; ++c4) {
      const uint4 hv = H4[c4];
      a00 = d2(hv.x, w0[4 * c4 + 0], a00);
      a01 = d2(hv.y, w0[4 * c4 + 1], a01);
      a10 = d2(hv.x, w1[4 * c4 + 0], a10);
      a11 = d2(hv.y, w1[4 * c4 + 1], a11);
      a00 = d2(hv.z, w0[4 * c4 + 2], a00);
      a01 = d2(hv.w, w0[4 * c4 + 3], a01);
      a10 = d2(hv.z, w1[4 * c4 + 2], a10);
      a11 = d2(hv.w, w1[4 * c4 + 3], a11);
    }
    if constexpr (NS4 > 0) {
#pragma unroll
      for (int u = 0; u < NS4; ++u) {
        const uint4 hv = H4[NRESP / 4 + u];
        const uint4 wv0 = ws0[u];
        const uint4 wv1 = ws1[u];
        a00 = d2(hv.x, wv0.x, a00);
        a01 = d2(hv.y, wv0.y, a01);
        a10 = d2(hv.x, wv1.x, a10);
        a11 = d2(hv.y, wv1.y, a11);
        a00 = d2(hv.z, wv0.z, a00);
        a01 = d2(hv.w, wv0.w, a01);
        a10 = d2(hv.z, wv1.z, a10);
        a11 = d2(hv.w, wv1.w, a11);
      }
    }
#pragma unroll
    for (int g = 0; g < 8; ++g) {
      const uint4 hv = H4[24 + g];
      const uint4 wv0 = wlds4[g * 1024 + r0];
      const uint4 wv1 = wlds4[g * 1024 + r1];
      a00 = d2(hv.x, wv0.x, a00);
      a01 = d2(hv.y, wv0.y, a01);
      a10 = d2(hv.x, wv1.x, a10);
      a11 = d2(hv.y, wv1.y, a11);
      a00 = d2(hv.z, wv0.z, a00);
      a01 = d2(hv.w, wv0.w, a01);
      a10 = d2(hv.z, wv1.z, a10);
      a11 = d2(hv.w, wv1.w, a11);
    }
    if constexpr (WIH) {
      if (cfg.wih) {
        const uint4* XS4 = (const uint4*)xsh;
#pragma unroll
        for (int u = 0; u < 16; ++u) {
          const uint4 xv = XS4[u];
          const uint4 wv0 = wi0[u];
          const uint4 wv1 = wi1[u];
          a00 = d2(xv.x, wv0.x, a00);
          a01 = d2(xv.y, wv0.y, a01);
          a10 = d2(xv.x, wv1.x, a10);
          a11 = d2(xv.y, wv1.y, a11);
          a00 = d2(xv.z, wv0.z, a00);
          a01 = d2(xv.w, wv0.w, a01);
          a10 = d2(xv.z, wv1.z, a10);
          a11 = d2(xv.w, wv1.w, a11);
        }
      }
    }

    gsm[r0] = a00 + a01 + xa0;
    gsm[r1] = a10 + a11 + xa1;
    __syncthreads();

    if (tid < 256) {
      const float gi = gsm[tid];
      const float gf = gsm[tid + 256];
      const float gg = gsm[tid + 512];
      const float go = gsm[tid + 768];
      const float cn = sigm(gf) * creg + sigm(gi) * tanh_(gg);
      const float hv = sigm(go) * tanh_(cn);
      creg = cn;
      const uint16_t hu = f2h(hv);
      h16[tid] = hu;
      if (histp && s < 1023) histp[(size_t)(s + 1) * 256 + tid] = hu;
    }
    __syncthreads();
  }

  if (cfg.hN && tid < 256) {
    cfg.hN[b * 256 + tid] = h2f(h16[tid]);
    cfg.cN[b * 256 + tid] = creg;
  }
}

// ---------------- output GEMM ----------------
__global__ __launch_bounds__(256) void k_out(const uint16_t* __restrict__ hist,
                                             const uint32_t* __restrict__ wlp,
                                             const float* __restrict__ lb,
                                             float* __restrict__ out, int outbase, int tsign) {
  const int b = blockIdx.y;
  const int t0 = blockIdx.x * 64;
  __shared__ __align__(16) uint32_t hq[64 * 128];
  const uint32_t* hsrc = (const uint32_t*)hist;
  for (int i = threadIdx.x; i < 64 * 128; i += 256) {
    hq[i] = hsrc[((size_t)b * 1024 + t0) * 128 + i];
  }
  __syncthreads();
  const int d = threadIdx.x & 127;
  const int th = threadIdx.x >> 7;
  float acc[32];
#pragma unroll
  for (int it = 0; it < 32; ++it) acc[it] = lb[d];
  const uint4* W4 = (const uint4*)(wlp + (size_t)d * 128);
  const uint4* HQ4 = (const uint4*)hq;
  for (int k2c = 0; k2c < 32; ++k2c) {
    const uint4 wv = W4[k2c];
#pragma unroll
    for (int it = 0; it < 32; ++it) {
      const int tl = th * 32 + it;
      const uint4 hv = HQ4[tl * 32 + k2c];
      acc[it] = d2(hv.x, wv.x, acc[it]);
      acc[it] = d2(hv.y, wv.y, acc[it]);
      acc[it] = d2(hv.z, wv.z, acc[it]);
      acc[it] = d2(hv.w, wv.w, acc[it]);
    }
  }
#pragma unroll
  for (int it = 0; it < 32; ++it) {
    const int tl = th * 32 + it;
    const int t = t0 + tl;
    const int tout = outbase + tsign * t;
    out[((size_t)b * Tv + tout) * Dv + d] = acc[it];
  }
}

// ---------------- host ----------------

extern "C" void kernel_launch(void* const* d_in, const int* in_sizes, int n_in,
                              void* d_out, int out_size, void* d_ws, size_t ws_size,
                              hipStream_t stream) {
  const float* x = (const float*)d_in[0];
  const float* e1_Wih = (const float*)d_in[1];
  const float* e1_Whh = (const float*)d_in[2];
  const float* e1_bih = (const float*)d_in[3];
  const float* e1_bhh = (const float*)d_in[4];
  const float* e2_Wih = (const float*)d_in[5];
  const float* e2_Whh = (const float*)d_in[6];
  const float* e2_bih = (const float*)d_in[7];
  const float* e2_bhh = (const float*)d_in[8];
  const float* d1_Wih = (const float*)d_in[9];
  const float* d1_Whh = (const float*)d_in[10];
  const float* d1_bih = (const float*)d_in[11];
  const float* d1_bhh = (const float*)d_in[12];
  const float* d2_Wih = (const float*)d_in[13];
  const float* d2_Whh = (const float*)d_in[14];
  const float* d2_bih = (const float*)d_in[15];
  const float* d2_bhh = (const float*)d_in[16];
  const float* l1_W = (const float*)d_in[17];
  const float* l1_b = (const float*)d_in[18];
  const float* l2_W = (const float*)d_in[19];
  const float* l2_b = (const float*)d_in[20];

  uint8_t* wsb = (uint8_t*)d_ws;
  size_t off = 0;
  auto take = [&](size_t n) -> void* {
    void* pp = wsb + off;
    off += (n + 255) & ~(size_t)255;
    return pp;
  };
  uint32_t* dppflag = (uint32_t*)take(256);
  uint32_t* xpk = (uint32_t*)take((size_t)Bv * Tv * 64 * 4);
  uint16_t* hist1 = (uint16_t*)take((size_t)Bv * T1v * Hv * 2);
  uint16_t* hist2 = (uint16_t*)take((size_t)Bv * T1v * Hv * 2);
  struct WSet {
    uint32_t *wAll, *wLg, *wStr48, *wih;
    float* bias;
    uint32_t *wReg, *wStrm, *wLds, *bpk;
  };
  auto take_wset = [&](bool with_ih) -> WSet {
    WSet w;
    w.wAll = (uint32_t*)take(128 * 1024 * 4);
    w.wLg = (uint32_t*)take(8 * 1024 * 16);
    w.wStr48 = (uint32_t*)take(1024 * 48 * 4);
    w.wih = with_ih ? (uint32_t*)take(1024 * 64 * 4) : nullptr;
    w.bias = (float*)take(1024 * 4);
    w.wReg = (uint32_t*)take(48 * 512 * 16);
    w.wStrm = (uint32_t*)take(2 * 16 * 512 * 16);
    w.wLds = (uint32_t*)take(16 * 512 * 16);
    w.bpk = (uint32_t*)take(128 * 16);
    return w;
  };
  WSet we1 = take_wset(true);
  WSet we2 = take_wset(true);
  WSet wd1 = take_wset(false);
  WSet wd2 = take_wset(false);
  float* wd32 = (float*)take(1024 * 256 * 4);
  uint32_t* wl1p = (uint32_t*)take(128 * 128 * 4);
  uint32_t* wl2p = (uint32_t*)take(128 * 128 * 4);
  float* h1 = (float*)take(64 * 256 * 4);
  float* c1 = (float*)take(64 * 256 * 4);
  float* h2 = (float*)take(64 * 256 * 4);
  float* c2 = (float*)take(64 * 256 * 4);
  uint16_t* xp = (uint16_t*)take((size_t)Bv * T1v * 1024 * 2);
  const bool use_xp = ws_size >= off;

  // ---- pick variant ----
  // 0: U2<5,1>  1: U2<5,2>  2: U2<4,2>  4: U6  5: rnn5<96>  6: rnn5<80>
  int variant = 6, RR = 0, SS = 0;
  {
    hipFuncAttributes fa;
    auto sf = [&](const void* f) {
      return hipFuncGetAttributes(&fa, f) == hipSuccess && fa.localSizeBytes == 0;
    };
    if (use_xp) {
      if (sf(reinterpret_cast<const void*>(&k_rnnU2<5, 1>))) { variant = 0; RR = 5; SS = 1; }
      else if (sf(reinterpret_cast<const void*>(&k_rnnU2<5, 2>))) { variant = 1; RR = 5; SS = 2; }
      else if (sf(reinterpret_cast<const void*>(&k_rnnU2<4, 2>))) { variant = 2; RR = 4; SS = 2; }
      else if (sf(reinterpret_cast<const void*>(&k_rnnU6))) variant = 4;
      else if (sf(reinterpret_cast<const void*>(&k_rnn5<96, false>))) variant = 5;
    } else {
      if (sf(reinterpret_cast<const void*>(&k_rnn5<96, true>))) variant = 5;
    }
  }

  // ---- common prep ----
  k_pack_x<<<(Bv * Tv * 64) / 256, 256, 0, stream>>>(x, xpk);
  k_pack_wih<<<256, 256, 0, stream>>>(e1_Wih, we1.wih);
  k_pack_wih<<<256, 256, 0, stream>>>(e2_Wih, we2.wih);
  k_bias2<<<4, 256, 0, stream>>>(e1_bih, e1_bhh, we1.bias);
  k_bias2<<<4, 256, 0, stream>>>(e2_bih, e2_bhh, we2.bias);
  k_pack_wl<<<64, 256, 0, stream>>>(l1_W, wl1p);
  k_pack_wl<<<64, 256, 0, stream>>>(l2_W, wl2p);

  if (variant <= 2) {
    k_dpp_probe<<<1, 64, 0, stream>>>(dppflag);
    k_pack_w3<<<512, 256, 0, stream>>>(e1_Whh, we1.wReg, we1.wStrm, we1.wLds, RR, SS);
    k_pack_w3<<<512, 256, 0, stream>>>(e2_Whh, we2.wReg, we2.wStrm, we2.wLds, RR, SS);
    k_bias_pack<<<1, 128, 0, stream>>>(we1.bias, we1.bpk);
    k_bias_pack<<<1, 128, 0, stream>>>(we2.bias, we2.bpk);
    k_dec_combine<<<1024, 256, 0, stream>>>(d1_Whh, d1_Wih, d1_bih, d1_bhh, l1_W, l1_b, wd32, wd1.bias);
    k_pack_w3<<<512, 256, 0, stream>>>(wd32, wd1.wReg, wd1.wStrm, wd1.wLds, RR, SS);
    k_bias_pack<<<1, 128, 0, stream>>>(wd1.bias, wd1.bpk);
    k_dec_combine<<<1024, 256, 0, stream>>>(d2_Whh, d2_Wih, d2_bih, d2_bhh, l2_W, l2_b, wd32, wd2.bias);
    k_pack_w3<<<512, 256, 0, stream>>>(wd32, wd2.wReg, wd2.wStrm, wd2.wLds, RR, SS);
    k_bias_pack<<<1, 128, 0, stream>>>(wd2.bias, wd2.bpk);

    auto mk = [&](WSet& w, const uint4* xps, const float* h0, const float* c0,
                  float* hN, float* cN, uint16_t* hist) -> CfgU {
      return CfgU{(const uint4*)w.wReg, (const uint4*)w.wStrm, (const uint4*)w.wLds,
                  (const uint4*)w.bpk, xps, h0, c0, hN, cN, hist, dppflag};
    };
    auto launch_u2 = [&](int grid, CfgU a, CfgU b2, int nA) {
      if (variant == 0)      k_rnnU2<5, 1><<<grid, 512, 0, stream>>>(a, b2, nA);
      else if (variant == 1) k_rnnU2<5, 2><<<grid, 512, 0, stream>>>(a, b2, nA);
      else                   k_rnnU2<4, 2><<<grid, 512, 0, stream>>>(a, b2, nA);
    };

    k_xp_gemm<0><<<dim3(4, 32, 64), 256, 0, stream>>>(xpk, we1.wih, xp, 1023, -1);
    CfgU e1c = mk(we1, (const uint4*)xp, nullptr, nullptr, h1, c1, nullptr);
    launch_u2(64, e1c, e1c, 64);

    k_xp_gemm<0><<<dim3(4, 32, 64), 256, 0, stream>>>(xpk, we2.wih, xp, 1024, 1);
    CfgU e2c = mk(we2, (const uint4*)xp, h1, c1, h2, c2, nullptr);
    CfgU d1c = mk(wd1, nullptr, h1, c1, nullptr, nullptr, hist1);
    launch_u2(128, e2c, d1c, 64);

    CfgU d2c = mk(wd2, nullptr, h2, c2, nullptr, nullptr, hist2);
    launch_u2(64, d2c, d2c, 64);
  } else if (variant == 4) {
    k_pack_w2<<<512, 256, 0, stream>>>(e1_Whh, we1.wReg, we1.wLds);
    k_pack_w2<<<512, 256, 0, stream>>>(e2_Whh, we2.wReg, we2.wLds);
    k_bias_pack<<<1, 128, 0, stream>>>(we1.bias, we1.bpk);
    k_bias_pack<<<1, 128, 0, stream>>>(we2.bias, we2.bpk);
    k_dec_combine<<<1024, 256, 0, stream>>>(d1_Whh, d1_Wih, d1_bih, d1_bhh, l1_W, l1_b, wd32, wd1.bias);
    k_pack_w2<<<512, 256, 0, stream>>>(wd32, wd1.wReg, wd1.wLds);
    k_bias_pack<<<1, 128, 0, stream>>>(wd1.bias, wd1.bpk);
    k_dec_combine<<<1024, 256, 0, stream>>>(d2_Whh, d2_Wih, d2_bih, d2_bhh, l2_W, l2_b, wd32, wd2.bias);
    k_pack_w2<<<512, 256, 0, stream>>>(wd32, wd2.wReg, wd2.wLds);
    k_bias_pack<<<1, 128, 0, stream>>>(wd2.bias, wd2.bpk);

    auto mk = [&](WSet& w, const uint4* xps, const float* h0, const float* c0,
                  float* hN, float* cN, uint16_t* hist) -> CfgU {
      return CfgU{(const uint4*)w.wReg, nullptr, (const uint4*)w.wLds,
                  (const uint4*)w.bpk, xps, h0, c0, hN, cN, hist, nullptr};
    };
    k_xp_gemm<0><<<dim3(4, 32, 64), 256, 0, stream>>>(xpk, we1.wih, xp, 1023, -1);
    CfgU e1c = mk(we1, (const uint4*)xp, nullptr, nullptr, h1, c1, nullptr);
    k_rnnU6<<<64, 512, 0, stream>>>(e1c, e1c, 64);

    k_xp_gemm<0><<<dim3(4, 32, 64), 256, 0, stream>>>(xpk, we2.wih, xp, 1024, 1);
    CfgU e2c = mk(we2, (const uint4*)xp, h1, c1, h2, c2, nullptr);
    CfgU d1c = mk(wd1, nullptr, h1, c1, nullptr, nullptr, hist1);
    k_rnnU6<<<128, 512, 0, stream>>>(e2c, d1c, 64);

    CfgU d2c = mk(wd2, nullptr, h2, c2, nullptr, nullptr, hist2);
    k_rnnU6<<<64, 512, 0, stream>>>(d2c, d2c, 64);
  } else {
    k_pack_w<<<512, 256, 0, stream>>>(e1_Whh, we1.wAll, we1.wLg, we1.wStr48);
    k_pack_w<<<512, 256, 0, stream>>>(e2_Whh, we2.wAll, we2.wLg, we2.wStr48);
    k_dec_combine<<<1024, 256, 0, stream>>>(d1_Whh, d1_Wih, d1_bih, d1_bhh, l1_W, l1_b, wd32, wd1.bias);
    k_pack_w<<<512, 256, 0, stream>>>(wd32, wd1.wAll, wd1.wLg, wd1.wStr48);
    k_dec_combine<<<1024, 256, 0, stream>>>(d2_Whh, d2_Wih, d2_bih, d2_bhh, l2_W, l2_b, wd32, wd2.bias);
    k_pack_w<<<512, 256, 0, stream>>>(wd32, wd2.wAll, wd2.wLg, wd2.wStr48);

    auto launch_old = [&](int grid, ChainCfg a, ChainCfg b2, int nA) {
      if (use_xp) {
        if (variant == 5) k_rnn5<96, false><<<grid, 512, 0, stream>>>(a, b2, nA);
        else              k_rnn5<80, false><<<grid, 512, 0, stream>>>(a, b2, nA);
      } else {
        if (variant == 5) k_rnn5<96, true><<<grid, 512, 0, stream>>>(a, b2, nA);
        else              k_rnn5<80, true><<<grid, 512, 0, stream>>>(a, b2, nA);
      }
    };
    if (use_xp) k_xp_gemm<1><<<dim3(4, 32, 64), 256, 0, stream>>>(xpk, we1.wih, xp, 1023, -1);
    ChainCfg e1c{we1.wAll, (const uint4*)we1.wLg, we1.wStr48, use_xp ? nullptr : we1.wih,
                 use_xp ? nullptr : xpk, use_xp ? xp : nullptr, we1.bias,
                 nullptr, nullptr, h1, c1, nullptr, 1023, -1};
    launch_old(64, e1c, e1c, 64);

    if (use_xp) k_xp_gemm<1><<<dim3(4, 32, 64), 256, 0, stream>>>(xpk, we2.wih, xp, 1024, 1);
    ChainCfg e2c{we2.wAll, (const uint4*)we2.wLg, we2.wStr48, use_xp ? nullptr : we2.wih,
                 use_xp ? nullptr : xpk, use_xp ? xp : nullptr, we2.bias,
                 h1, c1, h2, c2, nullptr, 1024, 1};
    ChainCfg d1c{wd1.wAll, (const uint4*)wd1.wLg, wd1.wStr48, nullptr, nullptr, nullptr,
                 wd1.bias, h1, c1, nullptr, nullptr, hist1, 0, 0};
    launch_old(128, e2c, d1c, 64);

    ChainCfg d2c{wd2.wAll, (const uint4*)wd2.wLg, wd2.wStr48, nullptr, nullptr, nullptr,
                 wd2.bias, h2, c2, nullptr, nullptr, hist2, 0, 0};
    launch_old(64, d2c, d2c, 64);
  }

  // ---- outputs ----
  k_out<<<dim3(16, 64), 256, 0, stream>>>(hist1, wl1p, l1_b, (float*)d_out, 0, 1);
  k_out<<<dim3(16, 64), 256, 0, stream>>>(hist2, wl2p, l2_b, (float*)d_out, 2047, -1);
}

// Round 9
// 7166.613 us; speedup vs baseline: 1.0185x; 1.0006x over previous
//
#include <hip/hip_runtime.h>
#include <stdint.h>

#define Bv 64
#define Tv 2048
#define T1v 1024
#define Dv 128
#define Hv 256

typedef _Float16 h2_t __attribute__((ext_vector_type(2)));
typedef _Float16 f16x8 __attribute__((ext_vector_type(8)));
typedef float f32x4 __attribute__((ext_vector_type(4)));

__device__ inline float d2(uint32_t hp, uint32_t wp, float acc) {
#if __has_builtin(__builtin_amdgcn_fdot2)
  return __builtin_amdgcn_fdot2(__builtin_bit_cast(h2_t, hp),
                                __builtin_bit_cast(h2_t, wp), acc, false);
#else
  float out;
  asm("v_dot2_f32_f16 %0, %1, %2, %3" : "=v"(out) : "v"(hp), "v"(wp), "v"(acc));
  return out;
#endif
}

__device__ inline uint16_t f2h(float x) {
  _Float16 h = (_Float16)x;
  return __builtin_bit_cast(uint16_t, h);
}
__device__ inline float h2f(uint16_t u) {
  return (float)__builtin_bit_cast(_Float16, u);
}
__device__ inline uint32_t packpair(float a, float b) {
  return (uint32_t)f2h(a) | ((uint32_t)f2h(b) << 16);
}
__device__ inline float unpk(uint32_t u, int hi) {
  return h2f((uint16_t)(hi ? (u >> 16) : (u & 0xffff)));
}
__device__ inline float sigm(float x) { return 1.f / (1.f + __expf(-x)); }
__device__ inline float tanh_(float x) { return 2.f / (1.f + __expf(-2.f * x)) - 1.f; }

__device__ inline float qsum4(float v) {
  int t = __builtin_amdgcn_update_dpp(0, __float_as_int(v), 0xB1, 0xF, 0xF, true);
  v += __int_as_float(t);
  t = __builtin_amdgcn_update_dpp(0, __float_as_int(v), 0x4E, 0xF, 0xF, true);
  return v + __int_as_float(t);
}

// ---------------- prep kernels ----------------

__global__ void k_pack_x(const float* __restrict__ x, uint32_t* __restrict__ xpk) {
  int idx = blockIdx.x * 256 + threadIdx.x;  // B*T*64
  const float2* x2 = (const float2*)x;
  float2 v = x2[idx];
  xpk[idx] = packpair(v.x, v.y);
}

// rnn5 fallback layout
__global__ void k_pack_w(const float* __restrict__ src, uint32_t* __restrict__ wAll,
                         uint32_t* __restrict__ wLg, uint32_t* __restrict__ wStr) {
  int idx = blockIdx.x * 256 + threadIdx.x;  // 1024*128
  int row = idx >> 7, k2 = idx & 127;
  uint32_t pr = packpair(src[row * 256 + 2 * k2], src[row * 256 + 2 * k2 + 1]);
  wAll[k2 * 1024 + row] = pr;
  if (k2 >= 96) {
    int g = (k2 - 96) >> 2, qq = (k2 - 96) & 3;
    wLg[(g * 1024 + row) * 4 + qq] = pr;
  }
  if (k2 >= 48 && k2 < 96) wStr[row * 48 + (k2 - 48)] = pr;
}

// U6 layout
__global__ void k_pack_w2(const float* __restrict__ src, uint32_t* __restrict__ wReg,
                          uint32_t* __restrict__ wLds) {
  int idx = blockIdx.x * 256 + threadIdx.x;  // 1024*128
  int r = idx >> 7, k2 = idx & 127;
  uint32_t pr = packpair(src[r * 256 + 2 * k2], src[r * 256 + 2 * k2 + 1]);
  int gate = r >> 8, u = r & 255;
  int u_hi = u >> 7, jb = u & 127;
  int q = k2 >> 5, kk = k2 & 31;
  int tid = jb * 4 + q;
  int ri = u_hi * 4 + gate;
  int cc = kk >> 2, c = kk & 3;
  if (cc < 6) wReg[((ri * 6 + cc) * 512 + tid) * 4 + c] = pr;
  else        wLds[((ri * 2 + (cc - 6)) * 512 + tid) * 4 + c] = pr;
}

// MFMA fragment pack: row' = unit*4+gate; tile t=row'>>4 (wave w=t>>3, tt=t&7);
// A-frag: lane = (row'&15) + 16*(kk>>3), dword=(kk&7)>>1. Chunk c=k>>5 classed
// into CR resident / CL LDS / CS stream (double image).
__global__ void k_pack_wf(const float* __restrict__ src, uint32_t* __restrict__ resF,
                          uint32_t* __restrict__ ldsF, uint32_t* __restrict__ strF,
                          int CR, int CL, int CS) {
  int idx = blockIdx.x * 256 + threadIdx.x;  // 1024*128
  int r = idx >> 7, k2 = idx & 127;
  int k = 2 * k2;
  uint32_t pr = packpair(src[r * 256 + k], src[r * 256 + k + 1]);
  int gate = r >> 8, u = r & 255;
  int rowp = u * 4 + gate;
  int t = rowp >> 4, w = t >> 3, tt = t & 7, rr = rowp & 15;
  int c = k >> 5, kk = k & 31;
  int lane = rr + 16 * (kk >> 3);
  int dw = (kk & 7) >> 1;
  if (c < CR) {
    resF[(((w * CR + c) * 8 + tt) * 64 + lane) * 4 + dw] = pr;
  } else if (c < CR + CL) {
    ldsF[(((w * CL + (c - CR)) * 8 + tt) * 64 + lane) * 4 + dw] = pr;
  } else {
    int cs = c - CR - CL;
    size_t o = (((size_t)(w * CS + cs) * 8 + tt) * 64 + lane) * 4 + dw;
    strF[o] = pr;
    strF[o + (size_t)CS * 4096 * 4] = pr;  // second image (anti-LICM)
  }
}

// bias in C-fragment order: biasF[(w*64+lane)*32 + tt*4 + reg] f16
__global__ void k_pack_biasf(const float* __restrict__ b32, uint16_t* __restrict__ biasF) {
  int r = blockIdx.x * 256 + threadIdx.x;
  if (r >= 1024) return;
  int gate = r >> 8, u = r & 255;
  int rowp = u * 4 + gate;
  int t = rowp >> 4, w = t >> 3, tt = t & 7, rr = rowp & 15;
  int lg = rr >> 2, reg = rr & 3;
  uint16_t v = f2h(b32[r]);
  for (int bl = 0; bl < 16; ++bl)
    biasF[(w * 64 + (bl + 16 * lg)) * 32 + tt * 4 + reg] = v;
}

// U6 packed bias
__global__ void k_bias_pack(const float* __restrict__ b32, uint32_t* __restrict__ bpk) {
  int jb = threadIdx.x;  // 128
  uint32_t w[4];
#pragma unroll
  for (int wi = 0; wi < 4; ++wi) {
    int ri0 = 2 * wi, ri1 = 2 * wi + 1;
    int row0 = (ri0 & 3) * 256 + jb + 128 * (ri0 >> 2);
    int row1 = (ri1 & 3) * 256 + jb + 128 * (ri1 >> 2);
    w[wi] = packpair(b32[row0], b32[row1]);
  }
  ((uint4*)bpk)[jb] = make_uint4(w[0], w[1], w[2], w[3]);
}

__global__ void k_pack_wih(const float* __restrict__ Wih, uint32_t* __restrict__ wihp) {
  int idx = blockIdx.x * 256 + threadIdx.x;  // 1024*64
  int row = idx >> 6, k2 = idx & 63;
  wihp[row * 64 + k2] = packpair(Wih[row * 128 + 2 * k2], Wih[row * 128 + 2 * k2 + 1]);
}

__global__ void k_bias2(const float* __restrict__ bih, const float* __restrict__ bhh,
                        float* __restrict__ bias) {
  int i = blockIdx.x * 256 + threadIdx.x;
  if (i < 1024) bias[i] = bih[i] + bhh[i];
}

__global__ void k_dec_combine(const float* __restrict__ Whh, const float* __restrict__ Wih,
                              const float* __restrict__ bih, const float* __restrict__ bhh,
                              const float* __restrict__ lW, const float* __restrict__ lb,
                              float* __restrict__ wd, float* __restrict__ bias) {
  int j = blockIdx.x;
  int k = threadIdx.x;
  __shared__ float wr[128];
  if (k < 128) wr[k] = Wih[j * 128 + k];
  __syncthreads();
  float acc = Whh[j * 256 + k];
  for (int d = 0; d < 128; ++d) acc += wr[d] * lW[d * 256 + k];
  wd[j * 256 + k] = acc;
  if (k == 0) {
    float s = bih[j] + bhh[j];
    for (int d = 0; d < 128; ++d) s += wr[d] * lb[d];
    bias[j] = s;
  }
}

__global__ void k_pack_wl(const float* __restrict__ lW, uint32_t* __restrict__ wlp) {
  int idx = blockIdx.x * 256 + threadIdx.x;  // 128*128
  int d = idx >> 7, k2 = idx & 127;
  wlp[d * 128 + k2] = packpair(lW[d * 256 + 2 * k2], lW[d * 256 + 2 * k2 + 1]);
}

// xp for U6 (LAY=0) and rnn5 (LAY=1)
template <int LAY>
__global__ __launch_bounds__(256) void k_xp_gemm(const uint32_t* __restrict__ xpk,
                                                 const uint32_t* __restrict__ wihp,
                                                 uint16_t* __restrict__ xp, int xt0, int xdt) {
  const int b = blockIdx.z;
  const int s0 = blockIdx.y * 32;
  const int r = blockIdx.x * 256 + threadIdx.x;
  uint32_t wreg[64];
#pragma unroll
  for (int k = 0; k < 64; ++k) wreg[k] = wihp[r * 64 + k];
  const int gate = r >> 8, u = r & 255;
  const int u_hi = u >> 7, jb = u & 127;
  const int ri = u_hi * 4 + gate;
  for (int sl = 0; sl < 32; ++sl) {
    const int s = s0 + sl;
    const int t = xt0 + s * xdt;
    const uint32_t* __restrict__ xrow = xpk + ((size_t)b * Tv + t) * 64;
    float a0 = 0.f, a1 = 0.f;
#pragma unroll
    for (int k = 0; k < 64; k += 2) {
      a0 = d2(xrow[k], wreg[k], a0);
      a1 = d2(xrow[k + 1], wreg[k + 1], a1);
    }
    uint16_t v = f2h(a0 + a1);
    if (LAY == 0)
      xp[(((size_t)b * T1v + s) * 128 + jb) * 8 + ri] = v;
    else
      xp[((size_t)b * T1v + s) * 1024 + r] = v;
  }
}

// xp in C-fragment order, bias pre-added:
// xpf[((bt*1024+s)*512 + w*64+lane)*32 + tt*4 + reg] f16
__global__ __launch_bounds__(256) void k_xp_gemmF(const uint32_t* __restrict__ xpk,
                                                  const uint32_t* __restrict__ wihp,
                                                  const float* __restrict__ bias,
                                                  uint16_t* __restrict__ xpf, int xt0, int xdt) {
  const int b = blockIdx.z;
  const int s0 = blockIdx.y * 32;
  const int r = blockIdx.x * 256 + threadIdx.x;
  uint32_t wreg[64];
#pragma unroll
  for (int k = 0; k < 64; ++k) wreg[k] = wihp[r * 64 + k];
  const float bv = bias[r];
  const int gate = r >> 8, u = r & 255;
  const int rowp = u * 4 + gate;
  const int t = rowp >> 4, w = t >> 3, tt = t & 7, rr = rowp & 15;
  const int lane = (b & 15) + 16 * (rr >> 2);
  const int reg = rr & 3;
  const int bt = b >> 4;
  for (int sl = 0; sl < 32; ++sl) {
    const int s = s0 + sl;
    const int tx = xt0 + s * xdt;
    const uint32_t* __restrict__ xrow = xpk + ((size_t)b * Tv + tx) * 64;
    float a0 = 0.f, a1 = 0.f;
#pragma unroll
    for (int k = 0; k < 64; k += 2) {
      a0 = d2(xrow[k], wreg[k], a0);
      a1 = d2(xrow[k + 1], wreg[k + 1], a1);
    }
    xpf[(((size_t)bt * 1024 + s) * 512 + w * 64 + lane) * 32 + tt * 4 + reg] =
        f2h(a0 + a1 + bv);
  }
}

// ---------------- MFMA recurrence kernel ----------------

struct CfgM {
  const uint4* resF;       // [8w][CR][8tt][64] uint4
  const uint4* ldsF;       // [8w][CL][8tt][64]
  const uint4* strF;       // 2 images [8w][CS][8tt][64]
  const uint16_t* biasF;   // [512][32] f16
  const uint16_t* xpf;     // [4bt][1024][512][32] f16 (bias included) or null
  const float* h0;         // [64][256] or null
  const float* c0;
  float* hN;
  float* cN;
  uint16_t* hist;          // [64][1024][256] or null
};

template <int CR, int CL, int CS>
__global__ void __launch_bounds__(512)
__attribute__((amdgpu_waves_per_eu(2, 2)))
k_rnnM(CfgM cA, CfgM cB, int nA) {
  __shared__ __align__(16) uint4 wldsA[CL > 0 ? CL * 4096 : 1];
  __shared__ __align__(16) uint16_t hb[2][16][264];  // padded rows (528B)

  const bool isA = (int)blockIdx.x < nA;
  const CfgM cfg = isA ? cA : cB;
  const int bi = isA ? (int)blockIdx.x : ((int)blockIdx.x - nA);
  const int b0 = bi * 16;
  const int tid = threadIdx.x;
  const int w = tid >> 6, l = tid & 63;
  const int bl = l & 15, lg = l >> 4;

  if (CL > 0) {
#pragma unroll
    for (int i = 0; i < CL * 8; ++i) wldsA[i * 512 + tid] = cfg.ldsF[i * 512 + tid];
  }

  uint4 wrA[CR * 8];
#pragma unroll
  for (int i = 0; i < CR * 8; ++i) wrA[i] = cfg.resF[((size_t)w * CR * 8 + i) * 64 + l];

  uint4 bh[4];
#pragma unroll
  for (int j = 0; j < 4; ++j) bh[j] = ((const uint4*)cfg.biasF)[(w * 64 + l) * 4 + j];

  float cst[8];
#pragma unroll
  for (int tt = 0; tt < 8; ++tt) {
    int unit = (w * 8 + tt) * 4 + lg;
    cst[tt] = cfg.c0 ? cfg.c0[(b0 + bl) * 256 + unit] : 0.f;
  }

  {
    int batch = tid >> 5, u0 = (tid & 31) * 8;
    uint16_t tmp[8];
#pragma unroll
    for (int j = 0; j < 8; ++j)
      tmp[j] = f2h(cfg.h0 ? cfg.h0[(b0 + batch) * 256 + u0 + j] : 0.f);
    *(uint4*)((char*)&hb[0][0][0] + batch * 528 + u0 * 2) = *(const uint4*)tmp;
  }
  __syncthreads();

  char* hb0 = (char*)&hb[0][0][0];
  const size_t hbsz = 16 * 264 * 2;
  int cur = 0;

  for (int s = 0; s < 1024; ++s) {
    const char* hbc = hb0 + (size_t)cur * hbsz;

    if (cfg.hist) {  // hist[s] = h_s (coalesced copy, fire-and-forget)
      int batch = tid >> 5, u0 = (tid & 31) * 8;
      uint4 hv = *(const uint4*)(hbc + batch * 528 + u0 * 2);
      *(uint4*)(cfg.hist + ((size_t)(b0 + batch) * 1024 + s) * 256 + u0) = hv;
    }

    f32x4 acc[8];
    if (cfg.xpf) {
      const uint4* xp4 = (const uint4*)(cfg.xpf + (((size_t)bi * 1024 + s) * 512 + tid) * 32);
      uint4 xh[4];
#pragma unroll
      for (int j = 0; j < 4; ++j) xh[j] = xp4[j];
      const _Float16* xv = (const _Float16*)xh;
#pragma unroll
      for (int tt = 0; tt < 8; ++tt)
#pragma unroll
        for (int rg = 0; rg < 4; ++rg) acc[tt][rg] = (float)xv[tt * 4 + rg];
    } else {
      const _Float16* bv = (const _Float16*)bh;
#pragma unroll
      for (int tt = 0; tt < 8; ++tt)
#pragma unroll
        for (int rg = 0; rg < 4; ++rg) acc[tt][rg] = (float)bv[tt * 4 + rg];
    }

#pragma unroll
    for (int c = 0; c < CR; ++c) {  // resident chunks
      f16x8 bf = __builtin_bit_cast(f16x8,
          *(const uint4*)(hbc + bl * 528 + c * 64 + lg * 16));
#pragma unroll
      for (int tt = 0; tt < 8; ++tt)
        acc[tt] = __builtin_amdgcn_mfma_f32_16x16x32_f16(
            __builtin_bit_cast(f16x8, wrA[c * 8 + tt]), bf, acc[tt], 0, 0, 0);
    }
    if (CL > 0) {
#pragma unroll
      for (int cl = 0; cl < CL; ++cl) {  // LDS chunks
        const int c = CR + cl;
        f16x8 bf = __builtin_bit_cast(f16x8,
            *(const uint4*)(hbc + bl * 528 + c * 64 + lg * 16));
#pragma unroll
        for (int tt = 0; tt < 8; ++tt) {
          uint4 au = wldsA[(w * CL + cl) * 512 + tt * 64 + l];
          acc[tt] = __builtin_amdgcn_mfma_f32_16x16x32_f16(
              __builtin_bit_cast(f16x8, au), bf, acc[tt], 0, 0, 0);
        }
      }
    }
    if (CS > 0) {  // streamed chunks (L2, double image), 1-ahead prefetch
      const uint4* sp = cfg.strF + ((s & 1) ? (size_t)CS * 4096 : 0);
      uint4 pf[8];
#pragma unroll
      for (int tt = 0; tt < 8; ++tt) pf[tt] = sp[((size_t)w * CS) * 512 + tt * 64 + l];
#pragma unroll
      for (int cs = 0; cs < CS; ++cs) {
        const int c = CR + CL + cs;
        uint4 cu[8];
#pragma unroll
        for (int tt = 0; tt < 8; ++tt) cu[tt] = pf[tt];
        if (cs + 1 < CS) {
#pragma unroll
          for (int tt = 0; tt < 8; ++tt)
            pf[tt] = sp[((size_t)w * CS + cs + 1) * 512 + tt * 64 + l];
        }
        f16x8 bf = __builtin_bit_cast(f16x8,
            *(const uint4*)(hbc + bl * 528 + c * 64 + lg * 16));
#pragma unroll
        for (int tt = 0; tt < 8; ++tt)
          acc[tt] = __builtin_amdgcn_mfma_f32_16x16x32_f16(
              __builtin_bit_cast(f16x8, cu[tt]), bf, acc[tt], 0, 0, 0);
      }
    }

    char* hbn = hb0 + (size_t)(cur ^ 1) * hbsz;
#pragma unroll
    for (int tt = 0; tt < 8; ++tt) {
      const float i_ = sigm(acc[tt][0]);
      const float f_ = sigm(acc[tt][1]);
      const float g_ = tanh_(acc[tt][2]);
      const float o_ = sigm(acc[tt][3]);
      const float cn = f_ * cst[tt] + i_ * g_;
      cst[tt] = cn;
      const float hv = o_ * tanh_(cn);
      const int unit = (w * 8 + tt) * 4 + lg;
      *(uint16_t*)(hbn + bl * 528 + unit * 2) = f2h(hv);
    }
    __syncthreads();
    cur ^= 1;
  }

  if (cfg.hN) {
    const char* hbc = hb0 + (size_t)cur * hbsz;
    int batch = tid >> 5, u0 = (tid & 31) * 8;
#pragma unroll
    for (int j = 0; j < 8; ++j)
      cfg.hN[(b0 + batch) * 256 + u0 + j] =
          h2f(*(const uint16_t*)(hbc + batch * 528 + (u0 + j) * 2));
#pragma unroll
    for (int tt = 0; tt < 8; ++tt) {
      int unit = (w * 8 + tt) * 4 + lg;
      cfg.cN[(b0 + bl) * 256 + unit] = cst[tt];
    }
  }
}

// ---------------- U6 (R6-proven fallback) ----------------

struct CfgU {
  const uint4* wA;
  const uint4* wC;
  const uint4* bpk;
  const uint4* xps;  // [B][1024][128] or null
  const float* h0;
  const float* c0;
  float* hN;
  float* cN;
  uint16_t* hist;
};

__global__ void __launch_bounds__(512)
__attribute__((amdgpu_waves_per_eu(2, 2)))
k_rnnU6(CfgU cA, CfgU cB, int nA) {
  __shared__ __align__(16) uint4 wldsM[2 * 8 * 512];
  __shared__ __align__(16) uint16_t hbuf[2][4][72];

  const bool isA = (int)blockIdx.x < nA;
  const CfgU cfg = isA ? cA : cB;
  const int b = isA ? (int)blockIdx.x : ((int)blockIdx.x - nA);
  const int tid = threadIdx.x;
  const int q = tid & 3, jb = tid >> 2;

#pragma unroll
  for (int i = 0; i < 16; ++i) wldsM[i * 512 + tid] = cfg.wC[i * 512 + tid];

  uint4 wr[8][6];
#pragma unroll
  for (int ri = 0; ri < 8; ++ri)
#pragma unroll
    for (int cc = 0; cc < 6; ++cc) wr[ri][cc] = cfg.wA[(ri * 6 + cc) * 512 + tid];

  const uint4 bp = cfg.bpk[jb];
  float c0r = cfg.c0 ? cfg.c0[b * 256 + jb] : 0.f;
  float c1r = cfg.c0 ? cfg.c0[b * 256 + jb + 128] : 0.f;

  uint16_t* histp = cfg.hist ? cfg.hist + (size_t)b * 1024 * 256 : nullptr;
  if (q == 0) {
    float h00 = cfg.h0 ? cfg.h0[b * 256 + jb] : 0.f;
    float h01 = cfg.h0 ? cfg.h0[b * 256 + jb + 128] : 0.f;
    uint16_t u0 = f2h(h00), u1 = f2h(h01);
    hbuf[0][jb >> 6][jb & 63] = u0;
    hbuf[0][2 + (jb >> 6)][jb & 63] = u1;
    if (histp) {
      histp[jb] = u0;
      histp[jb + 128] = u1;
    }
  }
  const uint4* xps4 = cfg.xps ? cfg.xps + (size_t)b * 1024 * 128 + jb : nullptr;

  __syncthreads();

  int cur = 0;
  for (int s = 0; s < 1024; ++s) {
    uint4 xq = make_uint4(0, 0, 0, 0);
    if (xps4) xq = xps4[(size_t)s * 128];
    const uint4* Hq = (const uint4*)(&hbuf[cur][q][0]);

    float acc[8];
#pragma unroll
    for (int ri = 0; ri < 8; ++ri) acc[ri] = 0.f;

#pragma unroll
    for (int cc = 0; cc < 6; ++cc) {
      const uint4 hv = Hq[cc];
#pragma unroll
      for (int ri = 0; ri < 8; ++ri) {
        acc[ri] = d2(hv.x, wr[ri][cc].x, acc[ri]);
        acc[ri] = d2(hv.y, wr[ri][cc].y, acc[ri]);
        acc[ri] = d2(hv.z, wr[ri][cc].z, acc[ri]);
        acc[ri] = d2(hv.w, wr[ri][cc].w, acc[ri]);
      }
    }
#pragma unroll
    for (int lI = 0; lI < 2; ++lI) {
      const uint4 hv = Hq[6 + lI];
#pragma unroll
      for (int ri = 0; ri < 8; ++ri) {
        const uint4 wv = wldsM[(ri * 2 + lI) * 512 + tid];
        acc[ri] = d2(hv.x, wv.x, acc[ri]);
        acc[ri] = d2(hv.y, wv.y, acc[ri]);
        acc[ri] = d2(hv.z, wv.z, acc[ri]);
        acc[ri] = d2(hv.w, wv.w, acc[ri]);
      }
    }

#pragma unroll
    for (int ri = 0; ri < 8; ++ri) acc[ri] = qsum4(acc[ri]);

    acc[0] += unpk(bp.x, 0) + unpk(xq.x, 0);
    acc[1] += unpk(bp.x, 1) + unpk(xq.x, 1);
    acc[2] += unpk(bp.y, 0) + unpk(xq.y, 0);
    acc[3] += unpk(bp.y, 1) + unpk(xq.y, 1);
    acc[4] += unpk(bp.z, 0) + unpk(xq.z, 0);
    acc[5] += unpk(bp.z, 1) + unpk(xq.z, 1);
    acc[6] += unpk(bp.w, 0) + unpk(xq.w, 0);
    acc[7] += unpk(bp.w, 1) + unpk(xq.w, 1);

    const float cn0 = sigm(acc[1]) * c0r + sigm(acc[0]) * tanh_(acc[2]);
    const float h0v = sigm(acc[3]) * tanh_(cn0);
    c0r = cn0;
    const float cn1 = sigm(acc[5]) * c1r + sigm(acc[4]) * tanh_(acc[6]);
    const float h1v = sigm(acc[7]) * tanh_(cn1);
    c1r = cn1;

    if (q == 0) {
      const uint16_t hu0 = f2h(h0v), hu1 = f2h(h1v);
      hbuf[cur ^ 1][jb >> 6][jb & 63] = hu0;
      hbuf[cur ^ 1][2 + (jb >> 6)][jb & 63] = hu1;
      if (histp && s < 1023) {
        histp[(size_t)(s + 1) * 256 + jb] = hu0;
        histp[(size_t)(s + 1) * 256 + jb + 128] = hu1;
      }
    }
    __syncthreads();
    cur ^= 1;
  }

  if (cfg.hN && q == 0) {
    cfg.hN[b * 256 + jb] = h2f(hbuf[cur][jb >> 6][jb & 63]);
    cfg.hN[b * 256 + jb + 128] = h2f(hbuf[cur][2 + (jb >> 6)][jb & 63]);
    cfg.cN[b * 256 + jb] = c0r;
    cfg.cN[b * 256 + jb + 128] = c1r;
  }
}

// ---------------- rnn5 (R4-proven deep fallback) ----------------

struct ChainCfg {
  const uint32_t* wAll;
  const uint4* wLg;
  const uint32_t* wStr;
  const uint32_t* wih;
  const uint32_t* xpk;
  const uint16_t* xps;
  const float* bias;
  const float* h0;
  const float* c0;
  float* hN;
  float* cN;
  uint16_t* hist;
  int xt0, xdt;
};

template <int NRESP, bool WIH>
__global__ void __launch_bounds__(512)
__attribute__((amdgpu_waves_per_eu(2, 2)))
k_rnn5(ChainCfg cA, ChainCfg cB, int nA) {
  __shared__ __align__(16) uint4 wlds4[8 * 1024];
  __shared__ float gsm[1024];
  __shared__ __align__(16) uint16_t h16[256];
  __shared__ __align__(16) uint32_t xsh[64];

  const bool isA = (int)blockIdx.x < nA;
  const ChainCfg cfg = isA ? cA : cB;
  const int b = isA ? (int)blockIdx.x : ((int)blockIdx.x - nA);
  const int tid = threadIdx.x;
  const int r0 = tid, r1 = tid + 512;

#pragma unroll
  for (int i = 0; i < 16; ++i) wlds4[i * 512 + tid] = cfg.wLg[i * 512 + tid];

  uint16_t* histp = cfg.hist ? cfg.hist + (size_t)b * 1024 * 256 : nullptr;

  float creg = 0.f;
  if (tid < 256) {
    float h0v = cfg.h0 ? cfg.h0[b * 256 + tid] : 0.f;
    creg = cfg.c0 ? cfg.c0[b * 256 + tid] : 0.f;
    uint16_t hu = f2h(h0v);
    h16[tid] = hu;
    if (histp) histp[tid] = hu;
  }

  uint32_t w0[NRESP], w1[NRESP];
#pragma unroll
  for (int k = 0; k < NRESP; ++k) w0[k] = cfg.wAll[k * 1024 + r0];
#pragma unroll
  for (int k = 0; k < NRESP; ++k) w1[k] = cfg.wAll[k * 1024 + r1];
  const float bias0 = cfg.bias[r0];
  const float bias1 = cfg.bias[r1];

  constexpr int NS4 = (96 - NRESP) / 4;
  const uint4* ws0 = (const uint4*)(cfg.wStr + (size_t)r0 * 48 + (NRESP - 48));
  const uint4* ws1 = (const uint4*)(cfg.wStr + (size_t)r1 * 48 + (NRESP - 48));
  const uint4* wi0 = cfg.wih ? (const uint4*)(cfg.wih + (size_t)r0 * 64) : nullptr;
  const uint4* wi1 = cfg.wih ? (const uint4*)(cfg.wih + (size_t)r1 * 64) : nullptr;
  const bool hasx = cfg.xps != nullptr;

  __syncthreads();

  for (int s = 0; s < 1024; ++s) {
    float xa0 = 0.f, xa1 = 0.f;
    if (hasx) {
      size_t xb = ((size_t)b * 1024 + s) * 1024;
      xa0 = h2f(cfg.xps[xb + r0]);
      xa1 = h2f(cfg.xps[xb + r1]);
    }
    if constexpr (WIH) {
      if (cfg.wih) {
        if (tid < 64) {
          const int t = cfg.xt0 + s * cfg.xdt;
          xsh[tid] = cfg.xpk[((size_t)b * Tv + t) * 64 + tid];
        }
        __syncthreads();
      }
    }

    const uint4* H4 = (const uint4*)h16;
    float a00 = bias0, a01 = 0.f, a10 = bias1, a11 = 0.f;

#pragma unroll
    for (int c4 = 0; c4 < NRESP / 4; ++c4) {
      const uint4 hv = H4[c4];
      a00 = d2(hv.x, w0[4 * c4 + 0], a00);
      a01 = d2(hv.y, w0[4 * c4 + 1], a01);
      a10 = d2(hv.x, w1[4 * c4 + 0], a10);
      a11 = d2(hv.y, w1[4 * c4 + 1], a11);
      a00 = d2(hv.z, w0[4 * c4 + 2], a00);
      a01 = d2(hv.w, w0[4 * c4 + 3], a01);
      a10 = d2(hv.z, w1[4 * c4 + 2], a10);
      a11 = d2(hv.w, w1[4 * c4 + 3], a11);
    }
    if constexpr (NS4 > 0) {
#pragma unroll
      for (int u = 0; u < NS4; ++u) {
        const uint4 hv = H4[NRESP / 4 + u];
        const uint4 wv0 = ws0[u];
        const uint4 wv1 = ws1[u];
        a00 = d2(hv.x, wv0.x, a00);
        a01 = d2(hv.y, wv0.y, a01);
        a10 = d2(hv.x, wv1.x, a10);
        a11 = d2(hv.y, wv1.y, a11);
        a00 = d2(hv.z, wv0.z, a00);
        a01 = d2(hv.w, wv0.w, a01);
        a10 = d2(hv.z, wv1.z, a10);
        a11 = d2(hv.w, wv1.w, a11);
      }
    }
#pragma unroll
    for (int g = 0; g < 8; ++g) {
      const uint4 hv = H4[24 + g];
      const uint4 wv0 = wlds4[g * 1024 + r0];
      const uint4 wv1 = wlds4[g * 1024 + r1];
      a00 = d2(hv.x, wv0.x, a00);
      a01 = d2(hv.y, wv0.y, a01);
      a10 = d2(hv.x, wv1.x, a10);
      a11 = d2(hv.y, wv1.y, a11);
      a00 = d2(hv.z, wv0.z, a00);
      a01 = d2(hv.w, wv0.w, a01);
      a10 = d2(hv.z, wv1.z, a10);
      a11 = d2(hv.w, wv1.w, a11);
    }
    if constexpr (WIH) {
      if (cfg.wih) {
        const uint4* XS4 = (const uint4*)xsh;
#pragma unroll
        for (int u = 0; u < 16; ++u) {
          const uint4 xv = XS4[u];
          const uint4 wv0 = wi0[u];
          const uint4 wv1 = wi1[u];
          a00 = d2(xv.x, wv0.x, a00);
          a01 = d2(xv.y, wv0.y, a01);
          a10 = d2(xv.x, wv1.x, a10);
          a11 = d2(xv.y, wv1.y, a11);
          a00 = d2(xv.z, wv0.z, a00);
          a01 = d2(xv.w, wv0.w, a01);
          a10 = d2(xv.z, wv1.z, a10);
          a11 = d2(xv.w, wv1.w, a11);
        }
      }
    }

    gsm[r0] = a00 + a01 + xa0;
    gsm[r1] = a10 + a11 + xa1;
    __syncthreads();

    if (tid < 256) {
      const float gi = gsm[tid];
      const float gf = gsm[tid + 256];
      const float gg = gsm[tid + 512];
      const float go = gsm[tid + 768];
      const float cn = sigm(gf) * creg + sigm(gi) * tanh_(gg);
      const float hv = sigm(go) * tanh_(cn);
      creg = cn;
      const uint16_t hu = f2h(hv);
      h16[tid] = hu;
      if (histp && s < 1023) histp[(size_t)(s + 1) * 256 + tid] = hu;
    }
    __syncthreads();
  }

  if (cfg.hN && tid < 256) {
    cfg.hN[b * 256 + tid] = h2f(h16[tid]);
    cfg.cN[b * 256 + tid] = creg;
  }
}

// ---------------- output GEMM ----------------
__global__ __launch_bounds__(256) void k_out(const uint16_t* __restrict__ hist,
                                             const uint32_t* __restrict__ wlp,
                                             const float* __restrict__ lb,
                                             float* __restrict__ out, int outbase, int tsign) {
  const int b = blockIdx.y;
  const int t0 = blockIdx.x * 64;
  __shared__ __align__(16) uint32_t hq[64 * 128];
  const uint32_t* hsrc = (const uint32_t*)hist;
  for (int i = threadIdx.x; i < 64 * 128; i += 256) {
    hq[i] = hsrc[((size_t)b * 1024 + t0) * 128 + i];
  }
  __syncthreads();
  const int d = threadIdx.x & 127;
  const int th = threadIdx.x >> 7;
  float acc[32];
#pragma unroll
  for (int it = 0; it < 32; ++it) acc[it] = lb[d];
  const uint4* W4 = (const uint4*)(wlp + (size_t)d * 128);
  const uint4* HQ4 = (const uint4*)hq;
  for (int k2c = 0; k2c < 32; ++k2c) {
    const uint4 wv = W4[k2c];
#pragma unroll
    for (int it = 0; it < 32; ++it) {
      const int tl = th * 32 + it;
      const uint4 hv = HQ4[tl * 32 + k2c];
      acc[it] = d2(hv.x, wv.x, acc[it]);
      acc[it] = d2(hv.y, wv.y, acc[it]);
      acc[it] = d2(hv.z, wv.z, acc[it]);
      acc[it] = d2(hv.w, wv.w, acc[it]);
    }
  }
#pragma unroll
  for (int it = 0; it < 32; ++it) {
    const int tl = th * 32 + it;
    const int t = t0 + tl;
    const int tout = outbase + tsign * t;
    out[((size_t)b * Tv + tout) * Dv + d] = acc[it];
  }
}

// ---------------- host ----------------

extern "C" void kernel_launch(void* const* d_in, const int* in_sizes, int n_in,
                              void* d_out, int out_size, void* d_ws, size_t ws_size,
                              hipStream_t stream) {
  const float* x = (const float*)d_in[0];
  const float* e1_Wih = (const float*)d_in[1];
  const float* e1_Whh = (const float*)d_in[2];
  const float* e1_bih = (const float*)d_in[3];
  const float* e1_bhh = (const float*)d_in[4];
  const float* e2_Wih = (const float*)d_in[5];
  const float* e2_Whh = (const float*)d_in[6];
  const float* e2_bih = (const float*)d_in[7];
  const float* e2_bhh = (const float*)d_in[8];
  const float* d1_Wih = (const float*)d_in[9];
  const float* d1_Whh = (const float*)d_in[10];
  const float* d1_bih = (const float*)d_in[11];
  const float* d1_bhh = (const float*)d_in[12];
  const float* d2_Wih = (const float*)d_in[13];
  const float* d2_Whh = (const float*)d_in[14];
  const float* d2_bih = (const float*)d_in[15];
  const float* d2_bhh = (const float*)d_in[16];
  const float* l1_W = (const float*)d_in[17];
  const float* l1_b = (const float*)d_in[18];
  const float* l2_W = (const float*)d_in[19];
  const float* l2_b = (const float*)d_in[20];

  uint8_t* wsb = (uint8_t*)d_ws;
  size_t off = 0;
  auto take = [&](size_t n) -> void* {
    void* pp = wsb + off;
    off += (n + 255) & ~(size_t)255;
    return pp;
  };
  uint32_t* xpk = (uint32_t*)take((size_t)Bv * Tv * 64 * 4);
  uint16_t* hist1 = (uint16_t*)take((size_t)Bv * T1v * Hv * 2);
  uint16_t* hist2 = (uint16_t*)take((size_t)Bv * T1v * Hv * 2);
  struct WSet {
    uint32_t *wAll, *wLg, *wStr48, *wih;
    float* bias;
    uint32_t *wReg, *wLds, *bpk;          // U6
    uint32_t *resF, *ldsF, *strF;         // MFMA
    uint16_t* biasF;
  };
  auto take_wset = [&](bool with_ih) -> WSet {
    WSet w;
    w.wAll = (uint32_t*)take(128 * 1024 * 4);
    w.wLg = (uint32_t*)take(8 * 1024 * 16);
    w.wStr48 = (uint32_t*)take(1024 * 48 * 4);
    w.wih = with_ih ? (uint32_t*)take(1024 * 64 * 4) : nullptr;
    w.bias = (float*)take(1024 * 4);
    w.wReg = (uint32_t*)take(48 * 512 * 16);
    w.wLds = (uint32_t*)take(16 * 512 * 16);
    w.bpk = (uint32_t*)take(128 * 16);
    w.resF = (uint32_t*)take((size_t)5 * 4096 * 16);      // up to CR=5
    w.ldsF = (uint32_t*)take((size_t)2 * 4096 * 16);      // up to CL=2
    w.strF = (uint32_t*)take((size_t)2 * 3 * 4096 * 16);  // 2 images, up to CS=3
    w.biasF = (uint16_t*)take(512 * 32 * 2);
    return w;
  };
  WSet we1 = take_wset(true);
  WSet we2 = take_wset(true);
  WSet wd1 = take_wset(false);
  WSet wd2 = take_wset(false);
  float* wd32 = (float*)take(1024 * 256 * 4);
  uint32_t* wl1p = (uint32_t*)take(128 * 128 * 4);
  uint32_t* wl2p = (uint32_t*)take(128 * 128 * 4);
  float* h1 = (float*)take(64 * 256 * 4);
  float* c1 = (float*)take(64 * 256 * 4);
  float* h2 = (float*)take(64 * 256 * 4);
  float* c2 = (float*)take(64 * 256 * 4);
  uint16_t* xp = (uint16_t*)take((size_t)Bv * T1v * 1024 * 2);  // 128 MiB, shared
  const bool use_xp = ws_size >= off;

  // ---- pick variant ----
  // 0: M<5,1,2>  1: M<4,2,2>  2: M<3,2,3>  3: U6  4: rnn5<96>  5: rnn5<80>
  int variant = 5;
  int MCR = 0, MCL = 0, MCS = 0;
  {
    hipFuncAttributes fa;
    auto sf = [&](const void* f) {
      return hipFuncGetAttributes(&fa, f) == hipSuccess && fa.localSizeBytes == 0;
    };
    if (use_xp) {
      if (sf(reinterpret_cast<const void*>(&k_rnnM<5, 1, 2>))) { variant = 0; MCR = 5; MCL = 1; MCS = 2; }
      else if (sf(reinterpret_cast<const void*>(&k_rnnM<4, 2, 2>))) { variant = 1; MCR = 4; MCL = 2; MCS = 2; }
      else if (sf(reinterpret_cast<const void*>(&k_rnnM<3, 2, 3>))) { variant = 2; MCR = 3; MCL = 2; MCS = 3; }
      else if (sf(reinterpret_cast<const void*>(&k_rnnU6))) variant = 3;
      else if (sf(reinterpret_cast<const void*>(&k_rnn5<96, false>))) variant = 4;
    } else {
      if (sf(reinterpret_cast<const void*>(&k_rnn5<96, true>))) variant = 4;
    }
  }

  // ---- common prep ----
  k_pack_x<<<(Bv * Tv * 64) / 256, 256, 0, stream>>>(x, xpk);
  k_pack_wih<<<256, 256, 0, stream>>>(e1_Wih, we1.wih);
  k_pack_wih<<<256, 256, 0, stream>>>(e2_Wih, we2.wih);
  k_bias2<<<4, 256, 0, stream>>>(e1_bih, e1_bhh, we1.bias);
  k_bias2<<<4, 256, 0, stream>>>(e2_bih, e2_bhh, we2.bias);
  k_pack_wl<<<64, 256, 0, stream>>>(l1_W, wl1p);
  k_pack_wl<<<64, 256, 0, stream>>>(l2_W, wl2p);

  if (variant <= 2) {
    // ---- MFMA path ----
    k_pack_wf<<<512, 256, 0, stream>>>(e1_Whh, we1.resF, we1.ldsF, we1.strF, MCR, MCL, MCS);
    k_pack_wf<<<512, 256, 0, stream>>>(e2_Whh, we2.resF, we2.ldsF, we2.strF, MCR, MCL, MCS);
    k_pack_biasf<<<4, 256, 0, stream>>>(we1.bias, we1.biasF);
    k_pack_biasf<<<4, 256, 0, stream>>>(we2.bias, we2.biasF);
    k_dec_combine<<<1024, 256, 0, stream>>>(d1_Whh, d1_Wih, d1_bih, d1_bhh, l1_W, l1_b, wd32, wd1.bias);
    k_pack_wf<<<512, 256, 0, stream>>>(wd32, wd1.resF, wd1.ldsF, wd1.strF, MCR, MCL, MCS);
    k_pack_biasf<<<4, 256, 0, stream>>>(wd1.bias, wd1.biasF);
    k_dec_combine<<<1024, 256, 0, stream>>>(d2_Whh, d2_Wih, d2_bih, d2_bhh, l2_W, l2_b, wd32, wd2.bias);
    k_pack_wf<<<512, 256, 0, stream>>>(wd32, wd2.resF, wd2.ldsF, wd2.strF, MCR, MCL, MCS);
    k_pack_biasf<<<4, 256, 0, stream>>>(wd2.bias, wd2.biasF);

    auto mk = [&](WSet& w, const uint16_t* xpf, const float* h0, const float* c0,
                  float* hN, float* cN, uint16_t* hist) -> CfgM {
      return CfgM{(const uint4*)w.resF, (const uint4*)w.ldsF, (const uint4*)w.strF,
                  w.biasF, xpf, h0, c0, hN, cN, hist};
    };
    auto launch_m = [&](int grid, CfgM a, CfgM b2, int nA) {
      if (variant == 0)      k_rnnM<5, 1, 2><<<grid, 512, 0, stream>>>(a, b2, nA);
      else if (variant == 1) k_rnnM<4, 2, 2><<<grid, 512, 0, stream>>>(a, b2, nA);
      else                   k_rnnM<3, 2, 3><<<grid, 512, 0, stream>>>(a, b2, nA);
    };

    k_xp_gemmF<<<dim3(4, 32, 64), 256, 0, stream>>>(xpk, we1.wih, we1.bias, xp, 1023, -1);
    CfgM e1c = mk(we1, xp, nullptr, nullptr, h1, c1, nullptr);
    launch_m(4, e1c, e1c, 4);

    k_xp_gemmF<<<dim3(4, 32, 64), 256, 0, stream>>>(xpk, we2.wih, we2.bias, xp, 1024, 1);
    CfgM e2c = mk(we2, xp, h1, c1, h2, c2, nullptr);
    CfgM d1c = mk(wd1, nullptr, h1, c1, nullptr, nullptr, hist1);
    launch_m(8, e2c, d1c, 4);

    CfgM d2c = mk(wd2, nullptr, h2, c2, nullptr, nullptr, hist2);
    launch_m(4, d2c, d2c, 4);
  } else if (variant == 3) {
    // ---- U6 path ----
    k_pack_w2<<<512, 256, 0, stream>>>(e1_Whh, we1.wReg, we1.wLds);
    k_pack_w2<<<512, 256, 0, stream>>>(e2_Whh, we2.wReg, we2.wLds);
    k_bias_pack<<<1, 128, 0, stream>>>(we1.bias, we1.bpk);
    k_bias_pack<<<1, 128, 0, stream>>>(we2.bias, we2.bpk);
    k_dec_combine<<<1024, 256, 0, stream>>>(d1_Whh, d1_Wih, d1_bih, d1_bhh, l1_W, l1_b, wd32, wd1.bias);
    k_pack_w2<<<512, 256, 0, stream>>>(wd32, wd1.wReg, wd1.wLds);
    k_bias_pack<<<1, 128, 0, stream>>>(wd1.bias, wd1.bpk);
    k_dec_combine<<<1024, 256, 0, stream>>>(d2_Whh, d2_Wih, d2_bih, d2_bhh, l2_W, l2_b, wd32, wd2.bias);
    k_pack_w2<<<512, 256, 0, stream>>>(wd32, wd2.wReg, wd2.wLds);
    k_bias_pack<<<1, 128, 0, stream>>>(wd2.bias, wd2.bpk);

    auto mk = [&](WSet& w, const uint4* xps, const float* h0, const float* c0,
                  float* hN, float* cN, uint16_t* hist) -> CfgU {
      return CfgU{(const uint4*)w.wReg, (const uint4*)w.wLds,
                  (const uint4*)w.bpk, xps, h0, c0, hN, cN, hist};
    };
    k_xp_gemm<0><<<dim3(4, 32, 64), 256, 0, stream>>>(xpk, we1.wih, xp, 1023, -1);
    CfgU e1c = mk(we1, (const uint4*)xp, nullptr, nullptr, h1, c1, nullptr);
    k_rnnU6<<<64, 512, 0, stream>>>(e1c, e1c, 64);

    k_xp_gemm<0><<<dim3(4, 32, 64), 256, 0, stream>>>(xpk, we2.wih, xp, 1024, 1);
    CfgU e2c = mk(we2, (const uint4*)xp, h1, c1, h2, c2, nullptr);
    CfgU d1c = mk(wd1, nullptr, h1, c1, nullptr, nullptr, hist1);
    k_rnnU6<<<128, 512, 0, stream>>>(e2c, d1c, 64);

    CfgU d2c = mk(wd2, nullptr, h2, c2, nullptr, nullptr, hist2);
    k_rnnU6<<<64, 512, 0, stream>>>(d2c, d2c, 64);
  } else {
    // ---- rnn5 deep fallback ----
    k_pack_w<<<512, 256, 0, stream>>>(e1_Whh, we1.wAll, we1.wLg, we1.wStr48);
    k_pack_w<<<512, 256, 0, stream>>>(e2_Whh, we2.wAll, we2.wLg, we2.wStr48);
    k_dec_combine<<<1024, 256, 0, stream>>>(d1_Whh, d1_Wih, d1_bih, d1_bhh, l1_W, l1_b, wd32, wd1.bias);
    k_pack_w<<<512, 256, 0, stream>>>(wd32, wd1.wAll, wd1.wLg, wd1.wStr48);
    k_dec_combine<<<1024, 256, 0, stream>>>(d2_Whh, d2_Wih, d2_bih, d2_bhh, l2_W, l2_b, wd32, wd2.bias);
    k_pack_w<<<512, 256, 0, stream>>>(wd32, wd2.wAll, wd2.wLg, wd2.wStr48);

    auto launch_old = [&](int grid, ChainCfg a, ChainCfg b2, int nA) {
      if (use_xp) {
        if (variant == 4) k_rnn5<96, false><<<grid, 512, 0, stream>>>(a, b2, nA);
        else              k_rnn5<80, false><<<grid, 512, 0, stream>>>(a, b2, nA);
      } else {
        if (variant == 4) k_rnn5<96, true><<<grid, 512, 0, stream>>>(a, b2, nA);
        else              k_rnn5<80, true><<<grid, 512, 0, stream>>>(a, b2, nA);
      }
    };
    if (use_xp) k_xp_gemm<1><<<dim3(4, 32, 64), 256, 0, stream>>>(xpk, we1.wih, xp, 1023, -1);
    ChainCfg e1c{we1.wAll, (const uint4*)we1.wLg, we1.wStr48, use_xp ? nullptr : we1.wih,
                 use_xp ? nullptr : xpk, use_xp ? xp : nullptr, we1.bias,
                 nullptr, nullptr, h1, c1, nullptr, 1023, -1};
    launch_old(64, e1c, e1c, 64);

    if (use_xp) k_xp_gemm<1><<<dim3(4, 32, 64), 256, 0, stream>>>(xpk, we2.wih, xp, 1024, 1);
    ChainCfg e2c{we2.wAll, (const uint4*)we2.wLg, we2.wStr48, use_xp ? nullptr : we2.wih,
                 use_xp ? nullptr : xpk, use_xp ? xp : nullptr, we2.bias,
                 h1, c1, h2, c2, nullptr, 1024, 1};
    ChainCfg d1c{wd1.wAll, (const uint4*)wd1.wLg, wd1.wStr48, nullptr, nullptr, nullptr,
                 wd1.bias, h1, c1, nullptr, nullptr, hist1, 0, 0};
    launch_old(128, e2c, d1c, 64);

    ChainCfg d2c{wd2.wAll, (const uint4*)wd2.wLg, wd2.wStr48, nullptr, nullptr, nullptr,
                 wd2.bias, h2, c2, nullptr, nullptr, hist2, 0, 0};
    launch_old(64, d2c, d2c, 64);
  }

  // ---- outputs ----
  k_out<<<dim3(16, 64), 256, 0, stream>>>(hist1, wl1p, l1_b, (float*)d_out, 0, 1);
  k_out<<<dim3(16, 64), 256, 0, stream>>>(hist2, wl2p, l2_b, (float*)d_out, 2047, -1);
}